// Round 5
// baseline (419.819 us; speedup 1.0000x reference)
//
#include <hip/hip_runtime.h>
#include <stdint.h>

// ---------------------------------------------------------------------------
// MLP_Model: candidates head + per-route Customer MLP + 2-layer GRU + FC head
// R8: gru_res phase restructured for MFMA/VALU pipe overlap:
//   T0-MFMAs -> T1-L1-MFMAs (own accs) -> T0-epilogues -> T1-L0-MFMAs
//   -> T1-epilogues -> barrier.
// The sched_barrier(0) that serialized the tiles is GONE; tile1's L1 gets
// separate accumulators so its MFMAs+ds_reads can hide tile0's
// transcendental epilogue (the measured VALU hot spot: ~96 trans/phase/wave).
// Cross-phase x prefetch dropped (x slice is 2KB/block, L2-hot; loaded at
// phase top, consumed at phase end). Sigmoid pair shares one rcp:
// inv=rcp((1+er)(1+ez)) -> 5 trans/element instead of 6.
// Reg budget/wave ~243 (<256 @ 2 waves/SIMD): weights 156 + accs 48 +
// h-state 16 + ax 8 + misc. mlp/final/pack unchanged.
// ws layout: [0,344064) packed bf16 weights; [344064,38092800) x2 bf16;
// [38092800,...) h1 final fp32 (~50.7 MB total).
// ---------------------------------------------------------------------------

#define NSEQ   24576   // 512 * 48
#define TSTEPS 24
#define SEQB   32      // sequences per gru block (2 tiles of 16)

typedef __attribute__((ext_vector_type(8))) short bf16x8;
typedef __attribute__((ext_vector_type(4))) float floatx4;

// packed-weight element offsets (uint16 units)
#define PK_W1    0
#define PK_W2    8192
#define PK_WIH0  12288
#define PK_WHH0  24576
#define PK_WIH1  73728
#define PK_WHH1  122880
#define PK_END   172032
#define X2_EL    172032                 // x2: [t][seq][32] bf16
#define HOUT_BYTE 38092800              // h1 final: [seq][128] fp32

#define MFMA(a,b,c) c = __builtin_amdgcn_mfma_f32_16x16x32_bf16(a, b, c, 0, 0, 0)

__device__ __forceinline__ uint16_t f2bf(float f) {
  uint32_t u = __float_as_uint(f);
  u += 0x7FFFu + ((u >> 16) & 1u);           // RNE
  return (uint16_t)(u >> 16);
}
// packed f32x2 -> bf16x2 (RNE), single VALU op. lo half = first arg.
__device__ __forceinline__ uint32_t cvt_pk(float a, float b) {
  uint32_t r;
  asm("v_cvt_pk_bf16_f32 %0, %1, %2" : "=v"(r) : "v"(a), "v"(b));
  return r;
}
__device__ __forceinline__ float fast_sigmoid(float x) {
  float e = __builtin_amdgcn_exp2f(-1.4426950408889634f * x);
  return __builtin_amdgcn_rcpf(1.0f + e);
}
__device__ __forceinline__ float fast_tanh(float x) {
  float e = __builtin_amdgcn_exp2f(-2.8853900817779268f * x);
  return 2.0f * __builtin_amdgcn_rcpf(1.0f + e) - 1.0f;
}
__device__ __forceinline__ bf16x8 ldf(const uint16_t* p) {
  return *(const bf16x8*)p;
}
// GRU gate combine, shared-rcp sigmoid pair: r=1/(1+er), z=1/(1+ez) via one
// rcp of the product. Exact algebra; denominators >= 1.
__device__ __forceinline__ floatx4 gru_gate(floatx4 gR, floatx4 gZ,
                                            floatx4 gN, floatx4 gH,
                                            floatx4 hprev) {
  floatx4 o;
  #pragma unroll
  for (int e = 0; e < 4; ++e) {
    float er = __builtin_amdgcn_exp2f(-1.4426950408889634f * gR[e]);
    float ez = __builtin_amdgcn_exp2f(-1.4426950408889634f * gZ[e]);
    float A = 1.0f + er, B = 1.0f + ez;
    float inv = __builtin_amdgcn_rcpf(A * B);
    float r = B * inv;
    float z = A * inv;
    float m = gN[e] + r * gH[e];
    float em = __builtin_amdgcn_exp2f(-2.8853900817779268f * m);
    float nn = 2.0f * __builtin_amdgcn_rcpf(1.0f + em) - 1.0f;
    o[e] = nn + z * (hprev[e] - nn);
  }
  return o;
}

// ---------------------------------------------------------------------------
// Kernel 0: pack all weights to bf16 fragment layout. (unchanged)
// ---------------------------------------------------------------------------
__global__ __launch_bounds__(256) void pack_weights(
    const float* __restrict__ w1, const float* __restrict__ w2,
    const float* __restrict__ wih0, const float* __restrict__ whh0,
    const float* __restrict__ wih1, const float* __restrict__ whh1,
    uint16_t* __restrict__ ws) {
  int idx = blockIdx.x * 256 + threadIdx.x;
  if (idx >= PK_END) return;
  const float* W; int N, KB, Kreal, base;
  if      (idx <  8192) { W = w1;   N = 128; KB = 2; Kreal = 36;  base = 0; }
  else if (idx < 12288) { W = w2;   N = 32;  KB = 4; Kreal = 128; base = 8192; }
  else if (idx < 24576) { W = wih0; N = 384; KB = 1; Kreal = 32;  base = 12288; }
  else if (idx < 73728) { W = whh0; N = 384; KB = 4; Kreal = 128; base = 24576; }
  else if (idx < 122880){ W = wih1; N = 384; KB = 4; Kreal = 128; base = 73728; }
  else                  { W = whh1; N = 384; KB = 4; Kreal = 128; base = 122880; }
  int li = idx - base;
  int frag = li >> 9;
  int e = li & 511;
  int lane = e >> 3, j = e & 7;
  int kb = frag % KB, nt = frag / KB;
  int k = kb * 32 + (lane >> 4) * 8 + j;
  int n = nt * 16 + (lane & 15);
  float v = (k < Kreal) ? W[k * N + n] : 0.0f;
  ws[base + li] = f2bf(v);
}

// ---------------------------------------------------------------------------
// Kernel 1: Customer MLP (unchanged from R5).
// ---------------------------------------------------------------------------
__global__ __launch_bounds__(256) void mlp_kernel(
    const float* __restrict__ customers, const float* __restrict__ b1,
    const float* __restrict__ b2, const uint16_t* __restrict__ wpk,
    uint16_t* __restrict__ x2out) {
  __shared__ uint16_t sA[128 * 136];
  const int r0 = blockIdx.x * 128;
  const int t  = r0 / NSEQ;
  const int s0 = r0 % NSEQ;
  const int tid = threadIdx.x;
  const int w = tid >> 6, l = tid & 63, q = l >> 4, c = l & 15;
  const int lo8 = l * 8;
  const int hb = 4 * q;                      // this lane's 4 rows within a tile

  floatx4 acc[2][8];
  #pragma unroll
  for (int mi = 0; mi < 2; ++mi)
    #pragma unroll
    for (int nt = 0; nt < 8; ++nt) acc[mi][nt] = (floatx4){0.f, 0.f, 0.f, 0.f};

  #pragma unroll
  for (int mi = 0; mi < 2; ++mi) {
    const int mt = 2 * w + mi;
    const int seq = s0 + mt * 16 + c;
    const float* xp = customers + (size_t)seq * 864 + t * 36;
    floatx4 u0 = *(const floatx4*)(xp + q * 8);
    floatx4 u1 = *(const floatx4*)(xp + q * 8 + 4);
    bf16x8 a0;
    { uint32_t* a0u = (uint32_t*)&a0;
      a0u[0] = cvt_pk(u0[0], u0[1]); a0u[1] = cvt_pk(u0[2], u0[3]);
      a0u[2] = cvt_pk(u1[0], u1[1]); a0u[3] = cvt_pk(u1[2], u1[3]); }
    bf16x8 a1x = (bf16x8){0,0,0,0,0,0,0,0};
    if (q == 0) {
      floatx4 u2 = *(const floatx4*)(xp + 32);
      uint32_t* a1u = (uint32_t*)&a1x;
      a1u[0] = cvt_pk(u2[0], u2[1]); a1u[1] = cvt_pk(u2[2], u2[3]);
    }
    #pragma unroll
    for (int nt = 0; nt < 8; ++nt) {
      bf16x8 bv0 = ldf(wpk + PK_W1 + (nt * 2 + 0) * 512 + lo8);
      bf16x8 bv1 = ldf(wpk + PK_W1 + (nt * 2 + 1) * 512 + lo8);
      MFMA(bv0, a0,  acc[mi][nt]);     // W1 as A, x as B -> D[hid][seq]
      MFMA(bv1, a1x, acc[mi][nt]);
    }
  }
  #pragma unroll
  for (int mi = 0; mi < 2; ++mi) {
    const int mt = 2 * w + mi;
    #pragma unroll
    for (int nt = 0; nt < 8; ++nt) {
      const floatx4 bv = *(const floatx4*)(b1 + nt * 16 + hb);
      float o0 = fast_tanh(acc[mi][nt][0] + bv[0]);
      float o1 = fast_tanh(acc[mi][nt][1] + bv[1]);
      float o2 = fast_tanh(acc[mi][nt][2] + bv[2]);
      float o3 = fast_tanh(acc[mi][nt][3] + bv[3]);
      uint2 pk; pk.x = cvt_pk(o0, o1); pk.y = cvt_pk(o2, o3);
      *(uint2*)&sA[(mt * 16 + c) * 136 + nt * 16 + hb] = pk;  // [seq][hid]
    }
  }
  __syncthreads();

  floatx4 acc2[2][2];
  #pragma unroll
  for (int mi = 0; mi < 2; ++mi)
    #pragma unroll
    for (int nt = 0; nt < 2; ++nt) acc2[mi][nt] = (floatx4){0.f, 0.f, 0.f, 0.f};

  #pragma unroll
  for (int kb = 0; kb < 4; ++kb) {
    bf16x8 av0 = ldf(&sA[((2 * w + 0) * 16 + c) * 136 + kb * 32 + q * 8]);
    bf16x8 av1 = ldf(&sA[((2 * w + 1) * 16 + c) * 136 + kb * 32 + q * 8]);
    #pragma unroll
    for (int nt = 0; nt < 2; ++nt) {
      bf16x8 bv = ldf(wpk + PK_W2 + (nt * 4 + kb) * 512 + lo8);
      MFMA(bv, av0, acc2[0][nt]);      // W2 as A, h as B -> D[out][seq]
      MFMA(bv, av1, acc2[1][nt]);
    }
  }
  #pragma unroll
  for (int mi = 0; mi < 2; ++mi) {
    const int mt = 2 * w + mi;
    #pragma unroll
    for (int nt = 0; nt < 2; ++nt) {
      const floatx4 bv = *(const floatx4*)(b2 + nt * 16 + hb);
      float o0 = fast_tanh(acc2[mi][nt][0] + bv[0]);
      float o1 = fast_tanh(acc2[mi][nt][1] + bv[1]);
      float o2 = fast_tanh(acc2[mi][nt][2] + bv[2]);
      float o3 = fast_tanh(acc2[mi][nt][3] + bv[3]);
      uint2 pk; pk.x = cvt_pk(o0, o1); pk.y = cvt_pk(o2, o3);
      *(uint2*)(x2out + (size_t)(r0 + mt * 16 + c) * 32 + nt * 16 + hb) = pk;
    }
  }
}

// ---------------------------------------------------------------------------
// Kernel 2 (R8): fused 2-layer GRU, single barrier per timestep, 32 seqs
// per block as two 16-seq tiles with cross-tile MFMA/epilogue overlap.
// Grid 768 (3 rounds of 1 block/CU). Wave J owns hidden cols [J*16,J*16+16).
// ---------------------------------------------------------------------------
__global__ __launch_bounds__(512, 2) void gru_res(
    const uint16_t* __restrict__ wpk, const uint16_t* __restrict__ x2,
    const float* __restrict__ bih0, const float* __restrict__ bhh0,
    const float* __restrict__ bih1, const float* __restrict__ bhh1,
    float* __restrict__ hout) {
  __shared__ uint16_t h0l[2][SEQB * 136];   // h0[t] double buffer (8704 B ea)
  __shared__ uint16_t h1l[2][SEQB * 136];   // h1[t] double buffer
  __shared__ float bias_l[8][128];          // R0,Z0,N0,H0,R1,Z1,N1,H1
  const int seq0 = blockIdx.x * SEQB;
  const int tid = threadIdx.x;
  const int J = tid >> 6, l = tid & 63, q = l >> 4, c = l & 15;
  const int lo8 = l * 8;

  // zero h1[-1]
  for (int i = tid; i < 2176; i += 512) ((uint32_t*)h1l[0])[i] = 0u;
  // bias table
  for (int i = tid; i < 1024; i += 512) {
    int g = i >> 7, k = i & 127;
    float v;
    if      (g == 0) v = bih0[k]       + bhh0[k];
    else if (g == 1) v = bih0[128 + k] + bhh0[128 + k];
    else if (g == 2) v = bih0[256 + k];
    else if (g == 3) v = bhh0[256 + k];
    else if (g == 4) v = bih1[k]       + bhh1[k];
    else if (g == 5) v = bih1[128 + k] + bhh1[128 + k];
    else if (g == 6) v = bih1[256 + k];
    else             v = bhh1[256 + k];
    bias_l[g][k] = v;
  }

  // ---- this wave's weight fragments (A-operands) into VGPRs (39 frags) ----
  bf16x8 wi0[3], wh0[3][4], wi1[3][4], wh1[3][4];
  #pragma unroll
  for (int g = 0; g < 3; ++g) {
    wi0[g] = ldf(wpk + PK_WIH0 + (g * 8 + J) * 512 + lo8);
    #pragma unroll
    for (int kb = 0; kb < 4; ++kb) {
      wh0[g][kb] = ldf(wpk + PK_WHH0 + ((g * 8 + J) * 4 + kb) * 512 + lo8);
      wi1[g][kb] = ldf(wpk + PK_WIH1 + ((g * 8 + J) * 4 + kb) * 512 + lo8);
      wh1[g][kb] = ldf(wpk + PK_WHH1 + ((g * 8 + J) * 4 + kb) * 512 + lo8);
    }
  }
  const int hb = J * 16 + 4 * q;     // this lane's 4 hidden cols (& bias idx)

  floatx4 h0m0 = (floatx4){0.f,0.f,0.f,0.f}, h0m1 = (floatx4){0.f,0.f,0.f,0.f};
  floatx4 h1m0 = (floatx4){0.f,0.f,0.f,0.f}, h1m1 = (floatx4){0.f,0.f,0.f,0.f};

  {  // x[0] for the prologue
    bf16x8 ax_0 = ldf(x2 + (size_t)(seq0 + c) * 32 + q * 8);
    bf16x8 ax_1 = ldf(x2 + (size_t)(seq0 + 16 + c) * 32 + q * 8);
    __syncthreads();   // bias_l + zeroed h1l[0] visible

    // ---- prologue: L0[0] with h0[-1]=0 (skip Whh MFMAs) -> h0l[0] ----
    floatx4 aR = *(const floatx4*)&bias_l[0][hb];
    floatx4 aZ = *(const floatx4*)&bias_l[1][hb];
    floatx4 aN = *(const floatx4*)&bias_l[2][hb];
    floatx4 aH = *(const floatx4*)&bias_l[3][hb];
    MFMA(wi0[0], ax_0, aR); MFMA(wi0[1], ax_0, aZ); MFMA(wi0[2], ax_0, aN);
    floatx4 bR = *(const floatx4*)&bias_l[0][hb];
    floatx4 bZ = *(const floatx4*)&bias_l[1][hb];
    floatx4 bN = *(const floatx4*)&bias_l[2][hb];
    floatx4 bH = *(const floatx4*)&bias_l[3][hb];
    MFMA(wi0[0], ax_1, bR); MFMA(wi0[1], ax_1, bZ); MFMA(wi0[2], ax_1, bN);
    h0m0 = gru_gate(aR, aZ, aN, aH, h0m0);
    h0m1 = gru_gate(bR, bZ, bN, bH, h0m1);
    { uint2 pk; pk.x = cvt_pk(h0m0[0], h0m0[1]); pk.y = cvt_pk(h0m0[2], h0m0[3]);
      *(uint2*)(h0l[0] + c * 136 + hb) = pk; }
    { uint2 pk; pk.x = cvt_pk(h0m1[0], h0m1[1]); pk.y = cvt_pk(h0m1[2], h0m1[3]);
      *(uint2*)(h0l[0] + (16 + c) * 136 + hb) = pk; }
  }
  __syncthreads();

  // ---- main: phase t = {L1[t], L0[t+1]} for both tiles, ONE barrier ----
  #pragma unroll 1
  for (int t = 0; t < TSTEPS; ++t) {
    const uint16_t* h0cur = h0l[t & 1];          // h0[t]
    const uint16_t* h1prv = h1l[t & 1];          // h1[t-1]
    uint16_t* h0nxt = h0l[(t + 1) & 1];          // h0[t+1]
    uint16_t* h1cur = h1l[(t + 1) & 1];          // h1[t]
    const int tn = (t + 1 < TSTEPS) ? t + 1 : t; // x[t+1] (t=23: dead work)
    bf16x8 ax0 = ldf(x2 + ((size_t)tn * NSEQ + seq0 + c) * 32 + q * 8);
    bf16x8 ax1 = ldf(x2 + ((size_t)tn * NSEQ + seq0 + 16 + c) * 32 + q * 8);

    // ---- T0: all MFMAs (L1[t] + L0[t+1]) ----
    floatx4 aR1 = *(const floatx4*)&bias_l[4][hb];
    floatx4 aZ1 = *(const floatx4*)&bias_l[5][hb];
    floatx4 aN1 = *(const floatx4*)&bias_l[6][hb];
    floatx4 aH1 = *(const floatx4*)&bias_l[7][hb];
    floatx4 aR0 = *(const floatx4*)&bias_l[0][hb];
    floatx4 aZ0 = *(const floatx4*)&bias_l[1][hb];
    floatx4 aN0 = *(const floatx4*)&bias_l[2][hb];
    floatx4 aH0 = *(const floatx4*)&bias_l[3][hb];
    #pragma unroll
    for (int kb = 0; kb < 4; ++kb) {
      bf16x8 a0 = ldf(h0cur + c * 136 + kb * 32 + q * 8);
      bf16x8 ah = ldf(h1prv + c * 136 + kb * 32 + q * 8);
      MFMA(wi1[0][kb], a0, aR1); MFMA(wh1[0][kb], ah, aR1);
      MFMA(wi1[1][kb], a0, aZ1); MFMA(wh1[1][kb], ah, aZ1);
      MFMA(wi1[2][kb], a0, aN1); MFMA(wh1[2][kb], ah, aH1);
      MFMA(wh0[0][kb], a0, aR0);
      MFMA(wh0[1][kb], a0, aZ0);
      MFMA(wh0[2][kb], a0, aH0);
    }
    MFMA(wi0[0], ax0, aR0); MFMA(wi0[1], ax0, aZ0); MFMA(wi0[2], ax0, aN0);

    // ---- T1: L1 MFMAs into SEPARATE accs (overlap with T0 epilogue) ----
    floatx4 bR1 = *(const floatx4*)&bias_l[4][hb];
    floatx4 bZ1 = *(const floatx4*)&bias_l[5][hb];
    floatx4 bN1 = *(const floatx4*)&bias_l[6][hb];
    floatx4 bH1 = *(const floatx4*)&bias_l[7][hb];
    #pragma unroll
    for (int kb = 0; kb < 4; ++kb) {
      bf16x8 b0 = ldf(h0cur + (16 + c) * 136 + kb * 32 + q * 8);
      bf16x8 bh = ldf(h1prv + (16 + c) * 136 + kb * 32 + q * 8);
      MFMA(wi1[0][kb], b0, bR1); MFMA(wh1[0][kb], bh, bR1);
      MFMA(wi1[1][kb], b0, bZ1); MFMA(wh1[1][kb], bh, bZ1);
      MFMA(wi1[2][kb], b0, bN1); MFMA(wh1[2][kb], bh, bH1);
    }

    // ---- T0 epilogues (trans chains hide under T1-L1 MFMAs above) ----
    h1m0 = gru_gate(aR1, aZ1, aN1, aH1, h1m0);
    { uint2 pk; pk.x = cvt_pk(h1m0[0], h1m0[1]); pk.y = cvt_pk(h1m0[2], h1m0[3]);
      *(uint2*)(h1cur + c * 136 + hb) = pk; }
    h0m0 = gru_gate(aR0, aZ0, aN0, aH0, h0m0);
    { uint2 pk; pk.x = cvt_pk(h0m0[0], h0m0[1]); pk.y = cvt_pk(h0m0[2], h0m0[3]);
      *(uint2*)(h0nxt + c * 136 + hb) = pk; }

    // ---- T1: L0 MFMAs ----
    floatx4 bR0 = *(const floatx4*)&bias_l[0][hb];
    floatx4 bZ0 = *(const floatx4*)&bias_l[1][hb];
    floatx4 bN0 = *(const floatx4*)&bias_l[2][hb];
    floatx4 bH0 = *(const floatx4*)&bias_l[3][hb];
    #pragma unroll
    for (int kb = 0; kb < 4; ++kb) {
      bf16x8 b0 = ldf(h0cur + (16 + c) * 136 + kb * 32 + q * 8);
      MFMA(wh0[0][kb], b0, bR0);
      MFMA(wh0[1][kb], b0, bZ0);
      MFMA(wh0[2][kb], b0, bH0);
    }
    MFMA(wi0[0], ax1, bR0); MFMA(wi0[1], ax1, bZ0); MFMA(wi0[2], ax1, bN0);

    // ---- T1 epilogues ----
    h1m1 = gru_gate(bR1, bZ1, bN1, bH1, h1m1);
    { uint2 pk; pk.x = cvt_pk(h1m1[0], h1m1[1]); pk.y = cvt_pk(h1m1[2], h1m1[3]);
      *(uint2*)(h1cur + (16 + c) * 136 + hb) = pk; }
    h0m1 = gru_gate(bR0, bZ0, bN0, bH0, h0m1);
    { uint2 pk; pk.x = cvt_pk(h0m1[0], h0m1[1]); pk.y = cvt_pk(h0m1[2], h0m1[3]);
      *(uint2*)(h0nxt + (16 + c) * 136 + hb) = pk; }

    __syncthreads();
  }

  *(floatx4*)(hout + (size_t)(seq0 + c) * 128 + hb) = h1m0;
  *(floatx4*)(hout + (size_t)(seq0 + 16 + c) * 128 + hb) = h1m1;
}

// ---------------------------------------------------------------------------
// Kernel 3: mean over routes + candidate head + fc1/fc2/fc3 (unchanged)
// ---------------------------------------------------------------------------
__global__ __launch_bounds__(192) void final_kernel(
    const float* __restrict__ hout, const float* __restrict__ cands,
    const float* __restrict__ cw, const float* __restrict__ cb,
    const float* __restrict__ f1w, const float* __restrict__ f1b,
    const float* __restrict__ f2w, const float* __restrict__ f2b,
    const float* __restrict__ f3w, const float* __restrict__ f3b,
    float* __restrict__ out) {
  __shared__ float hc[192];
  __shared__ float v1[128];
  __shared__ float v2[128];
  __shared__ float red[128];
  const int b = blockIdx.x, tid = threadIdx.x;
  if (tid < 128) {
    float s = 0.f;
    const float* hp = hout + (size_t)(b * 48) * 128 + tid;
    #pragma unroll 4
    for (int r = 0; r < 48; ++r) s += hp[r * 128];
    hc[tid] = s * (1.0f / 48.0f);
  } else {
    int j = tid - 128;
    float s = cb[j];
    const float* cp = cands + b * 72;
    #pragma unroll 8
    for (int k = 0; k < 72; ++k) s += cp[k] * cw[k * 64 + j];
    hc[128 + j] = s;
  }
  __syncthreads();
  if (tid < 128) {
    float s = f1b[tid];
    for (int k = 0; k < 192; ++k) s += hc[k] * f1w[k * 128 + tid];
    v1[tid] = fast_tanh(s);
  }
  __syncthreads();
  if (tid < 128) {
    float s = f2b[tid];
    for (int k = 0; k < 128; ++k) s += v1[k] * f2w[k * 128 + tid];
    v2[tid] = fast_tanh(s);
  }
  __syncthreads();
  if (tid < 128) red[tid] = v2[tid] * f3w[tid];
  __syncthreads();
  if (tid < 64) {
    float s = red[tid] + red[tid + 64];
    s += __shfl_down(s, 32);
    s += __shfl_down(s, 16);
    s += __shfl_down(s, 8);
    s += __shfl_down(s, 4);
    s += __shfl_down(s, 2);
    s += __shfl_down(s, 1);
    if (tid == 0) out[b] = s + f3b[0];
  }
}

// ---------------------------------------------------------------------------
extern "C" void kernel_launch(void* const* d_in, const int* in_sizes, int n_in,
                              void* d_out, int out_size, void* d_ws, size_t ws_size,
                              hipStream_t stream) {
  const float* cand  = (const float*)d_in[0];
  const float* cust  = (const float*)d_in[1];
  const float* w1    = (const float*)d_in[2];
  const float* b1    = (const float*)d_in[3];
  const float* w2    = (const float*)d_in[4];
  const float* b2    = (const float*)d_in[5];
  const float* wih0  = (const float*)d_in[6];
  const float* whh0  = (const float*)d_in[7];
  const float* bih0  = (const float*)d_in[8];
  const float* bhh0  = (const float*)d_in[9];
  const float* wih1  = (const float*)d_in[10];
  const float* whh1  = (const float*)d_in[11];
  const float* bih1  = (const float*)d_in[12];
  const float* bhh1  = (const float*)d_in[13];
  const float* cw    = (const float*)d_in[14];
  const float* cb    = (const float*)d_in[15];
  const float* f1w   = (const float*)d_in[16];
  const float* f1b   = (const float*)d_in[17];
  const float* f2w   = (const float*)d_in[18];
  const float* f2b   = (const float*)d_in[19];
  const float* f3w   = (const float*)d_in[20];
  const float* f3b   = (const float*)d_in[21];

  uint16_t* wsp = (uint16_t*)d_ws;
  uint16_t* x2p = wsp + X2_EL;
  float* hout = (float*)((char*)d_ws + HOUT_BYTE);
  float* outp = (float*)d_out;

  pack_weights<<<(PK_END + 255) / 256, 256, 0, stream>>>(w1, w2, wih0, whh0, wih1, whh1, wsp);
  mlp_kernel<<<(NSEQ * TSTEPS) / 128, 256, 0, stream>>>(cust, b1, b2, wsp, x2p);
  gru_res<<<NSEQ / SEQB, 512, 0, stream>>>(wsp, x2p, bih0, bhh0, bih1, bhh1, hout);
  final_kernel<<<512, 192, 0, stream>>>(hout, cand, cw, cb, f1w, f1b, f2w, f2b, f3w, f3b, outp);
}

// Round 6
// 417.605 us; speedup vs baseline: 1.0053x; 1.0053x over previous
//
#include <hip/hip_runtime.h>
#include <stdint.h>

// ---------------------------------------------------------------------------
// MLP_Model: candidates head + per-route Customer MLP + 2-layer GRU + FC head
// R9: gru_res reverted to R7 structure (known 219.7us; R8's hand interleave
// regressed to 238 via duplicated ds_reads + acc live-range blowup), keeping
// only R8's shared-rcp gru_gate (5 trans/elem). mlp_kernel t-blocked: block
// = 32 seqs x 4 timesteps (wave w owns t0+w), so customer reads are one
// contiguous 576B region per seq instead of scattered 144B pieces.
// ws layout: [0,344064) packed bf16 weights; [344064,38092800) x2 bf16;
// [38092800,...) h1 final fp32 (~50.7 MB total).
// ---------------------------------------------------------------------------

#define NSEQ   24576   // 512 * 48
#define TSTEPS 24
#define SEQB   32      // sequences per gru block (2 tiles of 16)

typedef __attribute__((ext_vector_type(8))) short bf16x8;
typedef __attribute__((ext_vector_type(4))) float floatx4;

// packed-weight element offsets (uint16 units)
#define PK_W1    0
#define PK_W2    8192
#define PK_WIH0  12288
#define PK_WHH0  24576
#define PK_WIH1  73728
#define PK_WHH1  122880
#define PK_END   172032
#define X2_EL    172032                 // x2: [t][seq][32] bf16
#define HOUT_BYTE 38092800              // h1 final: [seq][128] fp32

#define MFMA(a,b,c) c = __builtin_amdgcn_mfma_f32_16x16x32_bf16(a, b, c, 0, 0, 0)

__device__ __forceinline__ uint16_t f2bf(float f) {
  uint32_t u = __float_as_uint(f);
  u += 0x7FFFu + ((u >> 16) & 1u);           // RNE
  return (uint16_t)(u >> 16);
}
// packed f32x2 -> bf16x2 (RNE), single VALU op. lo half = first arg.
__device__ __forceinline__ uint32_t cvt_pk(float a, float b) {
  uint32_t r;
  asm("v_cvt_pk_bf16_f32 %0, %1, %2" : "=v"(r) : "v"(a), "v"(b));
  return r;
}
__device__ __forceinline__ float fast_sigmoid(float x) {
  float e = __builtin_amdgcn_exp2f(-1.4426950408889634f * x);
  return __builtin_amdgcn_rcpf(1.0f + e);
}
__device__ __forceinline__ float fast_tanh(float x) {
  float e = __builtin_amdgcn_exp2f(-2.8853900817779268f * x);
  return 2.0f * __builtin_amdgcn_rcpf(1.0f + e) - 1.0f;
}
__device__ __forceinline__ bf16x8 ldf(const uint16_t* p) {
  return *(const bf16x8*)p;
}
// GRU gate combine, shared-rcp sigmoid pair: r=1/(1+er), z=1/(1+ez) via one
// rcp of the product. Exact algebra; denominators >= 1. (validated in R8)
__device__ __forceinline__ floatx4 gru_gate(floatx4 gR, floatx4 gZ,
                                            floatx4 gN, floatx4 gH,
                                            floatx4 hprev) {
  floatx4 o;
  #pragma unroll
  for (int e = 0; e < 4; ++e) {
    float er = __builtin_amdgcn_exp2f(-1.4426950408889634f * gR[e]);
    float ez = __builtin_amdgcn_exp2f(-1.4426950408889634f * gZ[e]);
    float A = 1.0f + er, B = 1.0f + ez;
    float inv = __builtin_amdgcn_rcpf(A * B);
    float r = B * inv;
    float z = A * inv;
    float m = gN[e] + r * gH[e];
    float em = __builtin_amdgcn_exp2f(-2.8853900817779268f * m);
    float nn = 2.0f * __builtin_amdgcn_rcpf(1.0f + em) - 1.0f;
    o[e] = nn + z * (hprev[e] - nn);
  }
  return o;
}

// ---------------------------------------------------------------------------
// Kernel 0: pack all weights to bf16 fragment layout. (unchanged)
// ---------------------------------------------------------------------------
__global__ __launch_bounds__(256) void pack_weights(
    const float* __restrict__ w1, const float* __restrict__ w2,
    const float* __restrict__ wih0, const float* __restrict__ whh0,
    const float* __restrict__ wih1, const float* __restrict__ whh1,
    uint16_t* __restrict__ ws) {
  int idx = blockIdx.x * 256 + threadIdx.x;
  if (idx >= PK_END) return;
  const float* W; int N, KB, Kreal, base;
  if      (idx <  8192) { W = w1;   N = 128; KB = 2; Kreal = 36;  base = 0; }
  else if (idx < 12288) { W = w2;   N = 32;  KB = 4; Kreal = 128; base = 8192; }
  else if (idx < 24576) { W = wih0; N = 384; KB = 1; Kreal = 32;  base = 12288; }
  else if (idx < 73728) { W = whh0; N = 384; KB = 4; Kreal = 128; base = 24576; }
  else if (idx < 122880){ W = wih1; N = 384; KB = 4; Kreal = 128; base = 73728; }
  else                  { W = whh1; N = 384; KB = 4; Kreal = 128; base = 122880; }
  int li = idx - base;
  int frag = li >> 9;
  int e = li & 511;
  int lane = e >> 3, j = e & 7;
  int kb = frag % KB, nt = frag / KB;
  int k = kb * 32 + (lane >> 4) * 8 + j;
  int n = nt * 16 + (lane & 15);
  float v = (k < Kreal) ? W[k * N + n] : 0.0f;
  ws[base + li] = f2bf(v);
}

// ---------------------------------------------------------------------------
// Kernel 1: Customer MLP. R9: t-blocked — block = 32 seqs x 4 timesteps,
// wave w handles timestep t0+w (both 16-seq halves). Customer reads per seq
// become one contiguous 576B region (t0*36 .. t0*36+144 floats).
// ---------------------------------------------------------------------------
__global__ __launch_bounds__(256) void mlp_kernel(
    const float* __restrict__ customers, const float* __restrict__ b1,
    const float* __restrict__ b2, const uint16_t* __restrict__ wpk,
    uint16_t* __restrict__ x2out) {
  __shared__ uint16_t sA[128 * 136];
  const int sg = blockIdx.x % 768;           // seq group (32 seqs)
  const int tg = blockIdx.x / 768;           // t group (4 steps)
  const int s0 = sg * 32;
  const int t0 = tg * 4;
  const int tid = threadIdx.x;
  const int w = tid >> 6, l = tid & 63, q = l >> 4, c = l & 15;
  const int lo8 = l * 8;
  const int hb = 4 * q;                      // this lane's 4 rows within a tile
  const int tw = t0 + w;                     // this wave's timestep

  floatx4 acc[2][8];
  #pragma unroll
  for (int mi = 0; mi < 2; ++mi)
    #pragma unroll
    for (int nt = 0; nt < 8; ++nt) acc[mi][nt] = (floatx4){0.f, 0.f, 0.f, 0.f};

  #pragma unroll
  for (int mi = 0; mi < 2; ++mi) {
    const int seq = s0 + mi * 16 + c;
    const float* xp = customers + (size_t)seq * 864 + tw * 36;
    floatx4 u0 = *(const floatx4*)(xp + q * 8);
    floatx4 u1 = *(const floatx4*)(xp + q * 8 + 4);
    bf16x8 a0;
    { uint32_t* a0u = (uint32_t*)&a0;
      a0u[0] = cvt_pk(u0[0], u0[1]); a0u[1] = cvt_pk(u0[2], u0[3]);
      a0u[2] = cvt_pk(u1[0], u1[1]); a0u[3] = cvt_pk(u1[2], u1[3]); }
    bf16x8 a1x = (bf16x8){0,0,0,0,0,0,0,0};
    if (q == 0) {
      floatx4 u2 = *(const floatx4*)(xp + 32);
      uint32_t* a1u = (uint32_t*)&a1x;
      a1u[0] = cvt_pk(u2[0], u2[1]); a1u[1] = cvt_pk(u2[2], u2[3]);
    }
    #pragma unroll
    for (int nt = 0; nt < 8; ++nt) {
      bf16x8 bv0 = ldf(wpk + PK_W1 + (nt * 2 + 0) * 512 + lo8);
      bf16x8 bv1 = ldf(wpk + PK_W1 + (nt * 2 + 1) * 512 + lo8);
      MFMA(bv0, a0,  acc[mi][nt]);     // W1 as A, x as B -> D[hid][seq]
      MFMA(bv1, a1x, acc[mi][nt]);
    }
  }
  #pragma unroll
  for (int mi = 0; mi < 2; ++mi) {
    const int mt = 2 * w + mi;
    #pragma unroll
    for (int nt = 0; nt < 8; ++nt) {
      const floatx4 bv = *(const floatx4*)(b1 + nt * 16 + hb);
      float o0 = fast_tanh(acc[mi][nt][0] + bv[0]);
      float o1 = fast_tanh(acc[mi][nt][1] + bv[1]);
      float o2 = fast_tanh(acc[mi][nt][2] + bv[2]);
      float o3 = fast_tanh(acc[mi][nt][3] + bv[3]);
      uint2 pk; pk.x = cvt_pk(o0, o1); pk.y = cvt_pk(o2, o3);
      *(uint2*)&sA[(mt * 16 + c) * 136 + nt * 16 + hb] = pk;  // [local row][hid]
    }
  }
  __syncthreads();

  floatx4 acc2[2][2];
  #pragma unroll
  for (int mi = 0; mi < 2; ++mi)
    #pragma unroll
    for (int nt = 0; nt < 2; ++nt) acc2[mi][nt] = (floatx4){0.f, 0.f, 0.f, 0.f};

  #pragma unroll
  for (int kb = 0; kb < 4; ++kb) {
    bf16x8 av0 = ldf(&sA[((2 * w + 0) * 16 + c) * 136 + kb * 32 + q * 8]);
    bf16x8 av1 = ldf(&sA[((2 * w + 1) * 16 + c) * 136 + kb * 32 + q * 8]);
    #pragma unroll
    for (int nt = 0; nt < 2; ++nt) {
      bf16x8 bv = ldf(wpk + PK_W2 + (nt * 4 + kb) * 512 + lo8);
      MFMA(bv, av0, acc2[0][nt]);      // W2 as A, h as B -> D[out][seq]
      MFMA(bv, av1, acc2[1][nt]);
    }
  }
  #pragma unroll
  for (int mi = 0; mi < 2; ++mi) {
    const size_t grow = (size_t)tw * NSEQ + s0 + mi * 16 + c;
    #pragma unroll
    for (int nt = 0; nt < 2; ++nt) {
      const floatx4 bv = *(const floatx4*)(b2 + nt * 16 + hb);
      float o0 = fast_tanh(acc2[mi][nt][0] + bv[0]);
      float o1 = fast_tanh(acc2[mi][nt][1] + bv[1]);
      float o2 = fast_tanh(acc2[mi][nt][2] + bv[2]);
      float o3 = fast_tanh(acc2[mi][nt][3] + bv[3]);
      uint2 pk; pk.x = cvt_pk(o0, o1); pk.y = cvt_pk(o2, o3);
      *(uint2*)(x2out + grow * 32 + nt * 16 + hb) = pk;
    }
  }
}

// ---------------------------------------------------------------------------
// Kernel 2 (R9 = R7 structure + gru_gate): fused 2-layer GRU, single barrier
// per timestep, 32 seqs per block as two sequential 16-seq tiles with reused
// acc regs (sched_barrier(0) pins the split). Grid 768 (3 rounds of
// 1 block/CU). Wave J owns hidden cols [J*16,J*16+16).
// ---------------------------------------------------------------------------
__global__ __launch_bounds__(512, 2) void gru_res(
    const uint16_t* __restrict__ wpk, const uint16_t* __restrict__ x2,
    const float* __restrict__ bih0, const float* __restrict__ bhh0,
    const float* __restrict__ bih1, const float* __restrict__ bhh1,
    float* __restrict__ hout) {
  __shared__ uint16_t h0l[2][SEQB * 136];   // h0[t] double buffer (8704 B ea)
  __shared__ uint16_t h1l[2][SEQB * 136];   // h1[t] double buffer
  __shared__ float bias_l[8][128];          // R0,Z0,N0,H0,R1,Z1,N1,H1
  const int seq0 = blockIdx.x * SEQB;
  const int tid = threadIdx.x;
  const int J = tid >> 6, l = tid & 63, q = l >> 4, c = l & 15;
  const int lo8 = l * 8;

  // zero h1[-1]
  for (int i = tid; i < 2176; i += 512) ((uint32_t*)h1l[0])[i] = 0u;
  // bias table
  for (int i = tid; i < 1024; i += 512) {
    int g = i >> 7, k = i & 127;
    float v;
    if      (g == 0) v = bih0[k]       + bhh0[k];
    else if (g == 1) v = bih0[128 + k] + bhh0[128 + k];
    else if (g == 2) v = bih0[256 + k];
    else if (g == 3) v = bhh0[256 + k];
    else if (g == 4) v = bih1[k]       + bhh1[k];
    else if (g == 5) v = bih1[128 + k] + bhh1[128 + k];
    else if (g == 6) v = bih1[256 + k];
    else             v = bhh1[256 + k];
    bias_l[g][k] = v;
  }

  // ---- this wave's weight fragments (A-operands) into VGPRs (39 frags) ----
  bf16x8 wi0[3], wh0[3][4], wi1[3][4], wh1[3][4];
  #pragma unroll
  for (int g = 0; g < 3; ++g) {
    wi0[g] = ldf(wpk + PK_WIH0 + (g * 8 + J) * 512 + lo8);
    #pragma unroll
    for (int kb = 0; kb < 4; ++kb) {
      wh0[g][kb] = ldf(wpk + PK_WHH0 + ((g * 8 + J) * 4 + kb) * 512 + lo8);
      wi1[g][kb] = ldf(wpk + PK_WIH1 + ((g * 8 + J) * 4 + kb) * 512 + lo8);
      wh1[g][kb] = ldf(wpk + PK_WHH1 + ((g * 8 + J) * 4 + kb) * 512 + lo8);
    }
  }
  const int hb = J * 16 + 4 * q;     // this lane's 4 hidden cols (& bias idx)

  floatx4 h0m0 = (floatx4){0.f,0.f,0.f,0.f}, h0m1 = (floatx4){0.f,0.f,0.f,0.f};
  floatx4 h1m0 = (floatx4){0.f,0.f,0.f,0.f}, h1m1 = (floatx4){0.f,0.f,0.f,0.f};
  const floatx4 zero4 = (floatx4){0.f,0.f,0.f,0.f};

  bf16x8 ax_0 = ldf(x2 + (size_t)(seq0 + c) * 32 + q * 8);                 // x[0] t0
  bf16x8 ax_1 = ldf(x2 + (size_t)(seq0 + 16 + c) * 32 + q * 8);            // x[0] t1
  __syncthreads();   // bias_l + zeroed h1l[0] visible

  // ---- prologue: L0[0] with h0[-1]=0 (skip Whh MFMAs) -> h0l[0] ----
  #define GRU_PRO(TI, AX, H0M)                                              \
  {                                                                         \
    floatx4 aR = *(const floatx4*)&bias_l[0][hb];                           \
    floatx4 aZ = *(const floatx4*)&bias_l[1][hb];                           \
    floatx4 aN = *(const floatx4*)&bias_l[2][hb];                           \
    floatx4 aH = *(const floatx4*)&bias_l[3][hb];                           \
    MFMA(wi0[0], AX, aR); MFMA(wi0[1], AX, aZ); MFMA(wi0[2], AX, aN);       \
    H0M = gru_gate(aR, aZ, aN, aH, zero4);                                  \
    uint2 pk; pk.x = cvt_pk(H0M[0], H0M[1]); pk.y = cvt_pk(H0M[2], H0M[3]); \
    *(uint2*)(h0l[0] + ((TI) * 16 + c) * 136 + hb) = pk;                    \
  }
  GRU_PRO(0, ax_0, h0m0)
  GRU_PRO(1, ax_1, h0m1)
  #undef GRU_PRO
  __syncthreads();

  // x[1] for phase t=0
  ax_0 = ldf(x2 + ((size_t)NSEQ + seq0 + c) * 32 + q * 8);
  ax_1 = ldf(x2 + ((size_t)NSEQ + seq0 + 16 + c) * 32 + q * 8);

  // per-tile phase body: {L1[t], L0[t+1]} for 16 seqs, accs reused across tiles
  #define GRU_TILE(TI, AX, H0M, H1M)                                        \
  {                                                                         \
    floatx4 aR1 = *(const floatx4*)&bias_l[4][hb];                          \
    floatx4 aZ1 = *(const floatx4*)&bias_l[5][hb];                          \
    floatx4 aN1 = *(const floatx4*)&bias_l[6][hb];                          \
    floatx4 aH1 = *(const floatx4*)&bias_l[7][hb];                          \
    floatx4 aR0 = *(const floatx4*)&bias_l[0][hb];                          \
    floatx4 aZ0 = *(const floatx4*)&bias_l[1][hb];                          \
    floatx4 aN0 = *(const floatx4*)&bias_l[2][hb];                          \
    floatx4 aH0 = *(const floatx4*)&bias_l[3][hb];                          \
    _Pragma("unroll")                                                       \
    for (int kb = 0; kb < 4; ++kb) {                                        \
      bf16x8 a0 = ldf(h0cur + ((TI) * 16 + c) * 136 + kb * 32 + q * 8);     \
      bf16x8 ah = ldf(h1prv + ((TI) * 16 + c) * 136 + kb * 32 + q * 8);     \
      MFMA(wi1[0][kb], a0, aR1); MFMA(wh1[0][kb], ah, aR1);                 \
      MFMA(wi1[1][kb], a0, aZ1); MFMA(wh1[1][kb], ah, aZ1);                 \
      MFMA(wi1[2][kb], a0, aN1); MFMA(wh1[2][kb], ah, aH1);                 \
      MFMA(wh0[0][kb], a0, aR0);                                            \
      MFMA(wh0[1][kb], a0, aZ0);                                            \
      MFMA(wh0[2][kb], a0, aH0);                                            \
    }                                                                       \
    MFMA(wi0[0], AX, aR0); MFMA(wi0[1], AX, aZ0); MFMA(wi0[2], AX, aN0);    \
    { /* L1 epilogue -> h1[t] */                                            \
      H1M = gru_gate(aR1, aZ1, aN1, aH1, H1M);                              \
      uint2 pk; pk.x = cvt_pk(H1M[0], H1M[1]); pk.y = cvt_pk(H1M[2], H1M[3]);\
      *(uint2*)(h1cur + ((TI) * 16 + c) * 136 + hb) = pk;                   \
    }                                                                       \
    { /* L0 epilogue -> h0[t+1] */                                          \
      H0M = gru_gate(aR0, aZ0, aN0, aH0, H0M);                              \
      uint2 pk; pk.x = cvt_pk(H0M[0], H0M[1]); pk.y = cvt_pk(H0M[2], H0M[3]);\
      *(uint2*)(h0nxt + ((TI) * 16 + c) * 136 + hb) = pk;                   \
    }                                                                       \
  }

  #pragma unroll 1
  for (int t = 0; t < TSTEPS; ++t) {
    const uint16_t* h0cur = h0l[t & 1];          // h0[t]
    const uint16_t* h1prv = h1l[t & 1];          // h1[t-1]
    uint16_t* h0nxt = h0l[(t + 1) & 1];          // h0[t+1]
    uint16_t* h1cur = h1l[(t + 1) & 1];          // h1[t]
    const int tnx = (t + 2 < TSTEPS) ? t + 2 : TSTEPS - 1;
    bf16x8 axn_0 = ldf(x2 + ((size_t)tnx * NSEQ + seq0 + c) * 32 + q * 8);
    bf16x8 axn_1 = ldf(x2 + ((size_t)tnx * NSEQ + seq0 + 16 + c) * 32 + q * 8);

    GRU_TILE(0, ax_0, h0m0, h1m0)
    __builtin_amdgcn_sched_barrier(0);   // pin tile split: acc regs reused
    GRU_TILE(1, ax_1, h0m1, h1m1)

    __syncthreads();
    ax_0 = axn_0; ax_1 = axn_1;
  }
  #undef GRU_TILE

  *(floatx4*)(hout + (size_t)(seq0 + c) * 128 + hb) = h1m0;
  *(floatx4*)(hout + (size_t)(seq0 + 16 + c) * 128 + hb) = h1m1;
}

// ---------------------------------------------------------------------------
// Kernel 3: mean over routes + candidate head + fc1/fc2/fc3 (unchanged)
// ---------------------------------------------------------------------------
__global__ __launch_bounds__(192) void final_kernel(
    const float* __restrict__ hout, const float* __restrict__ cands,
    const float* __restrict__ cw, const float* __restrict__ cb,
    const float* __restrict__ f1w, const float* __restrict__ f1b,
    const float* __restrict__ f2w, const float* __restrict__ f2b,
    const float* __restrict__ f3w, const float* __restrict__ f3b,
    float* __restrict__ out) {
  __shared__ float hc[192];
  __shared__ float v1[128];
  __shared__ float v2[128];
  __shared__ float red[128];
  const int b = blockIdx.x, tid = threadIdx.x;
  if (tid < 128) {
    float s = 0.f;
    const float* hp = hout + (size_t)(b * 48) * 128 + tid;
    #pragma unroll 4
    for (int r = 0; r < 48; ++r) s += hp[r * 128];
    hc[tid] = s * (1.0f / 48.0f);
  } else {
    int j = tid - 128;
    float s = cb[j];
    const float* cp = cands + b * 72;
    #pragma unroll 8
    for (int k = 0; k < 72; ++k) s += cp[k] * cw[k * 64 + j];
    hc[128 + j] = s;
  }
  __syncthreads();
  if (tid < 128) {
    float s = f1b[tid];
    for (int k = 0; k < 192; ++k) s += hc[k] * f1w[k * 128 + tid];
    v1[tid] = fast_tanh(s);
  }
  __syncthreads();
  if (tid < 128) {
    float s = f2b[tid];
    for (int k = 0; k < 128; ++k) s += v1[k] * f2w[k * 128 + tid];
    v2[tid] = fast_tanh(s);
  }
  __syncthreads();
  if (tid < 128) red[tid] = v2[tid] * f3w[tid];
  __syncthreads();
  if (tid < 64) {
    float s = red[tid] + red[tid + 64];
    s += __shfl_down(s, 32);
    s += __shfl_down(s, 16);
    s += __shfl_down(s, 8);
    s += __shfl_down(s, 4);
    s += __shfl_down(s, 2);
    s += __shfl_down(s, 1);
    if (tid == 0) out[b] = s + f3b[0];
  }
}

// ---------------------------------------------------------------------------
extern "C" void kernel_launch(void* const* d_in, const int* in_sizes, int n_in,
                              void* d_out, int out_size, void* d_ws, size_t ws_size,
                              hipStream_t stream) {
  const float* cand  = (const float*)d_in[0];
  const float* cust  = (const float*)d_in[1];
  const float* w1    = (const float*)d_in[2];
  const float* b1    = (const float*)d_in[3];
  const float* w2    = (const float*)d_in[4];
  const float* b2    = (const float*)d_in[5];
  const float* wih0  = (const float*)d_in[6];
  const float* whh0  = (const float*)d_in[7];
  const float* bih0  = (const float*)d_in[8];
  const float* bhh0  = (const float*)d_in[9];
  const float* wih1  = (const float*)d_in[10];
  const float* whh1  = (const float*)d_in[11];
  const float* bih1  = (const float*)d_in[12];
  const float* bhh1  = (const float*)d_in[13];
  const float* cw    = (const float*)d_in[14];
  const float* cb    = (const float*)d_in[15];
  const float* f1w   = (const float*)d_in[16];
  const float* f1b   = (const float*)d_in[17];
  const float* f2w   = (const float*)d_in[18];
  const float* f2b   = (const float*)d_in[19];
  const float* f3w   = (const float*)d_in[20];
  const float* f3b   = (const float*)d_in[21];

  uint16_t* wsp = (uint16_t*)d_ws;
  uint16_t* x2p = wsp + X2_EL;
  float* hout = (float*)((char*)d_ws + HOUT_BYTE);
  float* outp = (float*)d_out;

  pack_weights<<<(PK_END + 255) / 256, 256, 0, stream>>>(w1, w2, wih0, whh0, wih1, whh1, wsp);
  mlp_kernel<<<(NSEQ * TSTEPS) / 128, 256, 0, stream>>>(cust, b1, b2, wsp, x2p);
  gru_res<<<NSEQ / SEQB, 512, 0, stream>>>(wsp, x2p, bih0, bhh0, bih1, bhh1, hout);
  final_kernel<<<512, 192, 0, stream>>>(hout, cand, cw, cb, f1w, f1b, f2w, f2b, f3w, f3b, outp);
}

// Round 7
// 407.174 us; speedup vs baseline: 1.0311x; 1.0256x over previous
//
#include <hip/hip_runtime.h>
#include <stdint.h>

// ---------------------------------------------------------------------------
// MLP_Model: candidates head + per-route Customer MLP + 2-layer GRU + FC head
// R10: gru_res epilogue reverted to R7's EXACT separate sigmoid/tanh form
// (R8/R9's shared-rcp gru_gate coupled the R/Z chains and cost ~15us in this
// dependency-bound regime). Last phase peeled: t=23 computes L1 only (h0[24]
// was dead work: 15 MFMAs + epilogue + stores + barrier saved). mlp stays
// t-blocked (R9). pack/final unchanged.
// ws layout: [0,344064) packed bf16 weights; [344064,38092800) x2 bf16;
// [38092800,...) h1 final fp32 (~50.7 MB total).
// ---------------------------------------------------------------------------

#define NSEQ   24576   // 512 * 48
#define TSTEPS 24
#define SEQB   32      // sequences per gru block (2 tiles of 16)

typedef __attribute__((ext_vector_type(8))) short bf16x8;
typedef __attribute__((ext_vector_type(4))) float floatx4;

// packed-weight element offsets (uint16 units)
#define PK_W1    0
#define PK_W2    8192
#define PK_WIH0  12288
#define PK_WHH0  24576
#define PK_WIH1  73728
#define PK_WHH1  122880
#define PK_END   172032
#define X2_EL    172032                 // x2: [t][seq][32] bf16
#define HOUT_BYTE 38092800              // h1 final: [seq][128] fp32

#define MFMA(a,b,c) c = __builtin_amdgcn_mfma_f32_16x16x32_bf16(a, b, c, 0, 0, 0)

__device__ __forceinline__ uint16_t f2bf(float f) {
  uint32_t u = __float_as_uint(f);
  u += 0x7FFFu + ((u >> 16) & 1u);           // RNE
  return (uint16_t)(u >> 16);
}
// packed f32x2 -> bf16x2 (RNE), single VALU op. lo half = first arg.
__device__ __forceinline__ uint32_t cvt_pk(float a, float b) {
  uint32_t r;
  asm("v_cvt_pk_bf16_f32 %0, %1, %2" : "=v"(r) : "v"(a), "v"(b));
  return r;
}
__device__ __forceinline__ float fast_sigmoid(float x) {
  float e = __builtin_amdgcn_exp2f(-1.4426950408889634f * x);
  return __builtin_amdgcn_rcpf(1.0f + e);
}
__device__ __forceinline__ float fast_tanh(float x) {
  float e = __builtin_amdgcn_exp2f(-2.8853900817779268f * x);
  return 2.0f * __builtin_amdgcn_rcpf(1.0f + e) - 1.0f;
}
__device__ __forceinline__ bf16x8 ldf(const uint16_t* p) {
  return *(const bf16x8*)p;
}

// ---------------------------------------------------------------------------
// Kernel 0: pack all weights to bf16 fragment layout. (unchanged)
// ---------------------------------------------------------------------------
__global__ __launch_bounds__(256) void pack_weights(
    const float* __restrict__ w1, const float* __restrict__ w2,
    const float* __restrict__ wih0, const float* __restrict__ whh0,
    const float* __restrict__ wih1, const float* __restrict__ whh1,
    uint16_t* __restrict__ ws) {
  int idx = blockIdx.x * 256 + threadIdx.x;
  if (idx >= PK_END) return;
  const float* W; int N, KB, Kreal, base;
  if      (idx <  8192) { W = w1;   N = 128; KB = 2; Kreal = 36;  base = 0; }
  else if (idx < 12288) { W = w2;   N = 32;  KB = 4; Kreal = 128; base = 8192; }
  else if (idx < 24576) { W = wih0; N = 384; KB = 1; Kreal = 32;  base = 12288; }
  else if (idx < 73728) { W = whh0; N = 384; KB = 4; Kreal = 128; base = 24576; }
  else if (idx < 122880){ W = wih1; N = 384; KB = 4; Kreal = 128; base = 73728; }
  else                  { W = whh1; N = 384; KB = 4; Kreal = 128; base = 122880; }
  int li = idx - base;
  int frag = li >> 9;
  int e = li & 511;
  int lane = e >> 3, j = e & 7;
  int kb = frag % KB, nt = frag / KB;
  int k = kb * 32 + (lane >> 4) * 8 + j;
  int n = nt * 16 + (lane & 15);
  float v = (k < Kreal) ? W[k * N + n] : 0.0f;
  ws[base + li] = f2bf(v);
}

// ---------------------------------------------------------------------------
// Kernel 1: Customer MLP. (unchanged from R9: t-blocked, 32 seqs x 4 steps)
// ---------------------------------------------------------------------------
__global__ __launch_bounds__(256) void mlp_kernel(
    const float* __restrict__ customers, const float* __restrict__ b1,
    const float* __restrict__ b2, const uint16_t* __restrict__ wpk,
    uint16_t* __restrict__ x2out) {
  __shared__ uint16_t sA[128 * 136];
  const int sg = blockIdx.x % 768;           // seq group (32 seqs)
  const int tg = blockIdx.x / 768;           // t group (4 steps)
  const int s0 = sg * 32;
  const int t0 = tg * 4;
  const int tid = threadIdx.x;
  const int w = tid >> 6, l = tid & 63, q = l >> 4, c = l & 15;
  const int lo8 = l * 8;
  const int hb = 4 * q;                      // this lane's 4 rows within a tile
  const int tw = t0 + w;                     // this wave's timestep

  floatx4 acc[2][8];
  #pragma unroll
  for (int mi = 0; mi < 2; ++mi)
    #pragma unroll
    for (int nt = 0; nt < 8; ++nt) acc[mi][nt] = (floatx4){0.f, 0.f, 0.f, 0.f};

  #pragma unroll
  for (int mi = 0; mi < 2; ++mi) {
    const int seq = s0 + mi * 16 + c;
    const float* xp = customers + (size_t)seq * 864 + tw * 36;
    floatx4 u0 = *(const floatx4*)(xp + q * 8);
    floatx4 u1 = *(const floatx4*)(xp + q * 8 + 4);
    bf16x8 a0;
    { uint32_t* a0u = (uint32_t*)&a0;
      a0u[0] = cvt_pk(u0[0], u0[1]); a0u[1] = cvt_pk(u0[2], u0[3]);
      a0u[2] = cvt_pk(u1[0], u1[1]); a0u[3] = cvt_pk(u1[2], u1[3]); }
    bf16x8 a1x = (bf16x8){0,0,0,0,0,0,0,0};
    if (q == 0) {
      floatx4 u2 = *(const floatx4*)(xp + 32);
      uint32_t* a1u = (uint32_t*)&a1x;
      a1u[0] = cvt_pk(u2[0], u2[1]); a1u[1] = cvt_pk(u2[2], u2[3]);
    }
    #pragma unroll
    for (int nt = 0; nt < 8; ++nt) {
      bf16x8 bv0 = ldf(wpk + PK_W1 + (nt * 2 + 0) * 512 + lo8);
      bf16x8 bv1 = ldf(wpk + PK_W1 + (nt * 2 + 1) * 512 + lo8);
      MFMA(bv0, a0,  acc[mi][nt]);     // W1 as A, x as B -> D[hid][seq]
      MFMA(bv1, a1x, acc[mi][nt]);
    }
  }
  #pragma unroll
  for (int mi = 0; mi < 2; ++mi) {
    const int mt = 2 * w + mi;
    #pragma unroll
    for (int nt = 0; nt < 8; ++nt) {
      const floatx4 bv = *(const floatx4*)(b1 + nt * 16 + hb);
      float o0 = fast_tanh(acc[mi][nt][0] + bv[0]);
      float o1 = fast_tanh(acc[mi][nt][1] + bv[1]);
      float o2 = fast_tanh(acc[mi][nt][2] + bv[2]);
      float o3 = fast_tanh(acc[mi][nt][3] + bv[3]);
      uint2 pk; pk.x = cvt_pk(o0, o1); pk.y = cvt_pk(o2, o3);
      *(uint2*)&sA[(mt * 16 + c) * 136 + nt * 16 + hb] = pk;  // [local row][hid]
    }
  }
  __syncthreads();

  floatx4 acc2[2][2];
  #pragma unroll
  for (int mi = 0; mi < 2; ++mi)
    #pragma unroll
    for (int nt = 0; nt < 2; ++nt) acc2[mi][nt] = (floatx4){0.f, 0.f, 0.f, 0.f};

  #pragma unroll
  for (int kb = 0; kb < 4; ++kb) {
    bf16x8 av0 = ldf(&sA[((2 * w + 0) * 16 + c) * 136 + kb * 32 + q * 8]);
    bf16x8 av1 = ldf(&sA[((2 * w + 1) * 16 + c) * 136 + kb * 32 + q * 8]);
    #pragma unroll
    for (int nt = 0; nt < 2; ++nt) {
      bf16x8 bv = ldf(wpk + PK_W2 + (nt * 4 + kb) * 512 + lo8);
      MFMA(bv, av0, acc2[0][nt]);      // W2 as A, h as B -> D[out][seq]
      MFMA(bv, av1, acc2[1][nt]);
    }
  }
  #pragma unroll
  for (int mi = 0; mi < 2; ++mi) {
    const size_t grow = (size_t)tw * NSEQ + s0 + mi * 16 + c;
    #pragma unroll
    for (int nt = 0; nt < 2; ++nt) {
      const floatx4 bv = *(const floatx4*)(b2 + nt * 16 + hb);
      float o0 = fast_tanh(acc2[mi][nt][0] + bv[0]);
      float o1 = fast_tanh(acc2[mi][nt][1] + bv[1]);
      float o2 = fast_tanh(acc2[mi][nt][2] + bv[2]);
      float o3 = fast_tanh(acc2[mi][nt][3] + bv[3]);
      uint2 pk; pk.x = cvt_pk(o0, o1); pk.y = cvt_pk(o2, o3);
      *(uint2*)(x2out + grow * 32 + nt * 16 + hb) = pk;
    }
  }
}

// ---------------------------------------------------------------------------
// Kernel 2 (R10 = R7 structure + R7 epilogue + last-phase peel): fused
// 2-layer GRU, single barrier per timestep, 32 seqs per block as two
// sequential 16-seq tiles with reused acc regs (sched_barrier(0) pins the
// split). Grid 768 (3 rounds of 1 block/CU). Wave J owns hidden cols
// [J*16,J*16+16). Final phase t=23 computes L1 only (h0[24] was dead).
// ---------------------------------------------------------------------------
__global__ __launch_bounds__(512, 2) void gru_res(
    const uint16_t* __restrict__ wpk, const uint16_t* __restrict__ x2,
    const float* __restrict__ bih0, const float* __restrict__ bhh0,
    const float* __restrict__ bih1, const float* __restrict__ bhh1,
    float* __restrict__ hout) {
  __shared__ uint16_t h0l[2][SEQB * 136];   // h0[t] double buffer (8704 B ea)
  __shared__ uint16_t h1l[2][SEQB * 136];   // h1[t] double buffer
  __shared__ float bias_l[8][128];          // R0,Z0,N0,H0,R1,Z1,N1,H1
  const int seq0 = blockIdx.x * SEQB;
  const int tid = threadIdx.x;
  const int J = tid >> 6, l = tid & 63, q = l >> 4, c = l & 15;
  const int lo8 = l * 8;

  // zero h1[-1]
  for (int i = tid; i < 2176; i += 512) ((uint32_t*)h1l[0])[i] = 0u;
  // bias table
  for (int i = tid; i < 1024; i += 512) {
    int g = i >> 7, k = i & 127;
    float v;
    if      (g == 0) v = bih0[k]       + bhh0[k];
    else if (g == 1) v = bih0[128 + k] + bhh0[128 + k];
    else if (g == 2) v = bih0[256 + k];
    else if (g == 3) v = bhh0[256 + k];
    else if (g == 4) v = bih1[k]       + bhh1[k];
    else if (g == 5) v = bih1[128 + k] + bhh1[128 + k];
    else if (g == 6) v = bih1[256 + k];
    else             v = bhh1[256 + k];
    bias_l[g][k] = v;
  }

  // ---- this wave's weight fragments (A-operands) into VGPRs (39 frags) ----
  bf16x8 wi0[3], wh0[3][4], wi1[3][4], wh1[3][4];
  #pragma unroll
  for (int g = 0; g < 3; ++g) {
    wi0[g] = ldf(wpk + PK_WIH0 + (g * 8 + J) * 512 + lo8);
    #pragma unroll
    for (int kb = 0; kb < 4; ++kb) {
      wh0[g][kb] = ldf(wpk + PK_WHH0 + ((g * 8 + J) * 4 + kb) * 512 + lo8);
      wi1[g][kb] = ldf(wpk + PK_WIH1 + ((g * 8 + J) * 4 + kb) * 512 + lo8);
      wh1[g][kb] = ldf(wpk + PK_WHH1 + ((g * 8 + J) * 4 + kb) * 512 + lo8);
    }
  }
  const int hb = J * 16 + 4 * q;     // this lane's 4 hidden cols (& bias idx)

  floatx4 h0m0 = (floatx4){0.f,0.f,0.f,0.f}, h0m1 = (floatx4){0.f,0.f,0.f,0.f};
  floatx4 h1m0 = (floatx4){0.f,0.f,0.f,0.f}, h1m1 = (floatx4){0.f,0.f,0.f,0.f};

  bf16x8 ax_0 = ldf(x2 + (size_t)(seq0 + c) * 32 + q * 8);                 // x[0] t0
  bf16x8 ax_1 = ldf(x2 + (size_t)(seq0 + 16 + c) * 32 + q * 8);            // x[0] t1
  __syncthreads();   // bias_l + zeroed h1l[0] visible

  // ---- prologue: L0[0] with h0[-1]=0 (skip Whh MFMAs) -> h0l[0] ----
  #define GRU_PRO(TI, AX, H0M)                                              \
  {                                                                         \
    floatx4 aR = *(const floatx4*)&bias_l[0][hb];                           \
    floatx4 aZ = *(const floatx4*)&bias_l[1][hb];                           \
    floatx4 aN = *(const floatx4*)&bias_l[2][hb];                           \
    floatx4 aH = *(const floatx4*)&bias_l[3][hb];                           \
    MFMA(wi0[0], AX, aR); MFMA(wi0[1], AX, aZ); MFMA(wi0[2], AX, aN);       \
    float o[4];                                                             \
    _Pragma("unroll")                                                       \
    for (int e = 0; e < 4; ++e) {                                           \
      float r  = fast_sigmoid(aR[e]);                                       \
      float zz = fast_sigmoid(aZ[e]);                                       \
      float nn = fast_tanh(aN[e] + r * aH[e]);                              \
      o[e] = nn - zz * nn;                                                  \
      H0M[e] = o[e];                                                        \
    }                                                                       \
    uint2 pk; pk.x = cvt_pk(o[0], o[1]); pk.y = cvt_pk(o[2], o[3]);         \
    *(uint2*)(h0l[0] + ((TI) * 16 + c) * 136 + hb) = pk;                    \
  }
  GRU_PRO(0, ax_0, h0m0)
  GRU_PRO(1, ax_1, h0m1)
  #undef GRU_PRO
  __syncthreads();

  // x[1] for phase t=0
  ax_0 = ldf(x2 + ((size_t)NSEQ + seq0 + c) * 32 + q * 8);
  ax_1 = ldf(x2 + ((size_t)NSEQ + seq0 + 16 + c) * 32 + q * 8);

  // per-tile phase body: {L1[t], L0[t+1]} for 16 seqs, accs reused across tiles
  #define GRU_TILE(TI, AX, H0M, H1M)                                        \
  {                                                                         \
    floatx4 aR1 = *(const floatx4*)&bias_l[4][hb];                          \
    floatx4 aZ1 = *(const floatx4*)&bias_l[5][hb];                          \
    floatx4 aN1 = *(const floatx4*)&bias_l[6][hb];                          \
    floatx4 aH1 = *(const floatx4*)&bias_l[7][hb];                          \
    floatx4 aR0 = *(const floatx4*)&bias_l[0][hb];                          \
    floatx4 aZ0 = *(const floatx4*)&bias_l[1][hb];                          \
    floatx4 aN0 = *(const floatx4*)&bias_l[2][hb];                          \
    floatx4 aH0 = *(const floatx4*)&bias_l[3][hb];                          \
    _Pragma("unroll")                                                       \
    for (int kb = 0; kb < 4; ++kb) {                                        \
      bf16x8 a0 = ldf(h0cur + ((TI) * 16 + c) * 136 + kb * 32 + q * 8);     \
      bf16x8 ah = ldf(h1prv + ((TI) * 16 + c) * 136 + kb * 32 + q * 8);     \
      MFMA(wi1[0][kb], a0, aR1); MFMA(wh1[0][kb], ah, aR1);                 \
      MFMA(wi1[1][kb], a0, aZ1); MFMA(wh1[1][kb], ah, aZ1);                 \
      MFMA(wi1[2][kb], a0, aN1); MFMA(wh1[2][kb], ah, aH1);                 \
      MFMA(wh0[0][kb], a0, aR0);                                            \
      MFMA(wh0[1][kb], a0, aZ0);                                            \
      MFMA(wh0[2][kb], a0, aH0);                                            \
    }                                                                       \
    MFMA(wi0[0], AX, aR0); MFMA(wi0[1], AX, aZ0); MFMA(wi0[2], AX, aN0);    \
    { /* L1 epilogue -> h1[t] */                                            \
      float o[4];                                                           \
      _Pragma("unroll")                                                     \
      for (int e = 0; e < 4; ++e) {                                         \
        float r  = fast_sigmoid(aR1[e]);                                    \
        float zz = fast_sigmoid(aZ1[e]);                                    \
        float nn = fast_tanh(aN1[e] + r * aH1[e]);                          \
        o[e] = nn + zz * (H1M[e] - nn);                                     \
        H1M[e] = o[e];                                                      \
      }                                                                     \
      uint2 pk; pk.x = cvt_pk(o[0], o[1]); pk.y = cvt_pk(o[2], o[3]);       \
      *(uint2*)(h1cur + ((TI) * 16 + c) * 136 + hb) = pk;                   \
    }                                                                       \
    { /* L0 epilogue -> h0[t+1] */                                          \
      float o[4];                                                           \
      _Pragma("unroll")                                                     \
      for (int e = 0; e < 4; ++e) {                                         \
        float r  = fast_sigmoid(aR0[e]);                                    \
        float zz = fast_sigmoid(aZ0[e]);                                    \
        float nn = fast_tanh(aN0[e] + r * aH0[e]);                          \
        o[e] = nn + zz * (H0M[e] - nn);                                     \
        H0M[e] = o[e];                                                      \
      }                                                                     \
      uint2 pk; pk.x = cvt_pk(o[0], o[1]); pk.y = cvt_pk(o[2], o[3]);       \
      *(uint2*)(h0nxt + ((TI) * 16 + c) * 136 + hb) = pk;                   \
    }                                                                       \
  }

  #pragma unroll 1
  for (int t = 0; t < TSTEPS - 1; ++t) {
    const uint16_t* h0cur = h0l[t & 1];          // h0[t]
    const uint16_t* h1prv = h1l[t & 1];          // h1[t-1]
    uint16_t* h0nxt = h0l[(t + 1) & 1];          // h0[t+1]
    uint16_t* h1cur = h1l[(t + 1) & 1];          // h1[t]
    const int tnx = (t + 2 < TSTEPS) ? t + 2 : TSTEPS - 1;
    bf16x8 axn_0 = ldf(x2 + ((size_t)tnx * NSEQ + seq0 + c) * 32 + q * 8);
    bf16x8 axn_1 = ldf(x2 + ((size_t)tnx * NSEQ + seq0 + 16 + c) * 32 + q * 8);

    GRU_TILE(0, ax_0, h0m0, h1m0)
    __builtin_amdgcn_sched_barrier(0);   // pin tile split: acc regs reused
    GRU_TILE(1, ax_1, h0m1, h1m1)

    __syncthreads();
    ax_0 = axn_0; ax_1 = axn_1;
  }
  #undef GRU_TILE

  // ---- peeled final phase t=23: L1 only, no LDS stores, no barrier ----
  {
    const int t = TSTEPS - 1;
    const uint16_t* h0cur = h0l[t & 1];          // h0[23]
    const uint16_t* h1prv = h1l[t & 1];          // h1[22]
    #define GRU_LAST(TI, H1M)                                               \
    {                                                                       \
      floatx4 aR1 = *(const floatx4*)&bias_l[4][hb];                        \
      floatx4 aZ1 = *(const floatx4*)&bias_l[5][hb];                        \
      floatx4 aN1 = *(const floatx4*)&bias_l[6][hb];                        \
      floatx4 aH1 = *(const floatx4*)&bias_l[7][hb];                        \
      _Pragma("unroll")                                                     \
      for (int kb = 0; kb < 4; ++kb) {                                      \
        bf16x8 a0 = ldf(h0cur + ((TI) * 16 + c) * 136 + kb * 32 + q * 8);   \
        bf16x8 ah = ldf(h1prv + ((TI) * 16 + c) * 136 + kb * 32 + q * 8);   \
        MFMA(wi1[0][kb], a0, aR1); MFMA(wh1[0][kb], ah, aR1);               \
        MFMA(wi1[1][kb], a0, aZ1); MFMA(wh1[1][kb], ah, aZ1);               \
        MFMA(wi1[2][kb], a0, aN1); MFMA(wh1[2][kb], ah, aH1);               \
      }                                                                     \
      _Pragma("unroll")                                                     \
      for (int e = 0; e < 4; ++e) {                                         \
        float r  = fast_sigmoid(aR1[e]);                                    \
        float zz = fast_sigmoid(aZ1[e]);                                    \
        float nn = fast_tanh(aN1[e] + r * aH1[e]);                          \
        H1M[e] = nn + zz * (H1M[e] - nn);                                   \
      }                                                                     \
    }
    GRU_LAST(0, h1m0)
    GRU_LAST(1, h1m1)
    #undef GRU_LAST
  }

  *(floatx4*)(hout + (size_t)(seq0 + c) * 128 + hb) = h1m0;
  *(floatx4*)(hout + (size_t)(seq0 + 16 + c) * 128 + hb) = h1m1;
}

// ---------------------------------------------------------------------------
// Kernel 3: mean over routes + candidate head + fc1/fc2/fc3 (unchanged)
// ---------------------------------------------------------------------------
__global__ __launch_bounds__(192) void final_kernel(
    const float* __restrict__ hout, const float* __restrict__ cands,
    const float* __restrict__ cw, const float* __restrict__ cb,
    const float* __restrict__ f1w, const float* __restrict__ f1b,
    const float* __restrict__ f2w, const float* __restrict__ f2b,
    const float* __restrict__ f3w, const float* __restrict__ f3b,
    float* __restrict__ out) {
  __shared__ float hc[192];
  __shared__ float v1[128];
  __shared__ float v2[128];
  __shared__ float red[128];
  const int b = blockIdx.x, tid = threadIdx.x;
  if (tid < 128) {
    float s = 0.f;
    const float* hp = hout + (size_t)(b * 48) * 128 + tid;
    #pragma unroll 4
    for (int r = 0; r < 48; ++r) s += hp[r * 128];
    hc[tid] = s * (1.0f / 48.0f);
  } else {
    int j = tid - 128;
    float s = cb[j];
    const float* cp = cands + b * 72;
    #pragma unroll 8
    for (int k = 0; k < 72; ++k) s += cp[k] * cw[k * 64 + j];
    hc[128 + j] = s;
  }
  __syncthreads();
  if (tid < 128) {
    float s = f1b[tid];
    for (int k = 0; k < 192; ++k) s += hc[k] * f1w[k * 128 + tid];
    v1[tid] = fast_tanh(s);
  }
  __syncthreads();
  if (tid < 128) {
    float s = f2b[tid];
    for (int k = 0; k < 128; ++k) s += v1[k] * f2w[k * 128 + tid];
    v2[tid] = fast_tanh(s);
  }
  __syncthreads();
  if (tid < 128) red[tid] = v2[tid] * f3w[tid];
  __syncthreads();
  if (tid < 64) {
    float s = red[tid] + red[tid + 64];
    s += __shfl_down(s, 32);
    s += __shfl_down(s, 16);
    s += __shfl_down(s, 8);
    s += __shfl_down(s, 4);
    s += __shfl_down(s, 2);
    s += __shfl_down(s, 1);
    if (tid == 0) out[b] = s + f3b[0];
  }
}

// ---------------------------------------------------------------------------
extern "C" void kernel_launch(void* const* d_in, const int* in_sizes, int n_in,
                              void* d_out, int out_size, void* d_ws, size_t ws_size,
                              hipStream_t stream) {
  const float* cand  = (const float*)d_in[0];
  const float* cust  = (const float*)d_in[1];
  const float* w1    = (const float*)d_in[2];
  const float* b1    = (const float*)d_in[3];
  const float* w2    = (const float*)d_in[4];
  const float* b2    = (const float*)d_in[5];
  const float* wih0  = (const float*)d_in[6];
  const float* whh0  = (const float*)d_in[7];
  const float* bih0  = (const float*)d_in[8];
  const float* bhh0  = (const float*)d_in[9];
  const float* wih1  = (const float*)d_in[10];
  const float* whh1  = (const float*)d_in[11];
  const float* bih1  = (const float*)d_in[12];
  const float* bhh1  = (const float*)d_in[13];
  const float* cw    = (const float*)d_in[14];
  const float* cb    = (const float*)d_in[15];
  const float* f1w   = (const float*)d_in[16];
  const float* f1b   = (const float*)d_in[17];
  const float* f2w   = (const float*)d_in[18];
  const float* f2b   = (const float*)d_in[19];
  const float* f3w   = (const float*)d_in[20];
  const float* f3b   = (const float*)d_in[21];

  uint16_t* wsp = (uint16_t*)d_ws;
  uint16_t* x2p = wsp + X2_EL;
  float* hout = (float*)((char*)d_ws + HOUT_BYTE);
  float* outp = (float*)d_out;

  pack_weights<<<(PK_END + 255) / 256, 256, 0, stream>>>(w1, w2, wih0, whh0, wih1, whh1, wsp);
  mlp_kernel<<<(NSEQ * TSTEPS) / 128, 256, 0, stream>>>(cust, b1, b2, wsp, x2p);
  gru_res<<<NSEQ / SEQB, 512, 0, stream>>>(wsp, x2p, bih0, bhh0, bih1, bhh1, hout);
  final_kernel<<<512, 192, 0, stream>>>(hout, cand, cw, cb, f1w, f1b, f2w, f2b, f3w, f3b, outp);
}

// Round 8
// 404.383 us; speedup vs baseline: 1.0382x; 1.0069x over previous
//
#include <hip/hip_runtime.h>
#include <stdint.h>

// ---------------------------------------------------------------------------
// MLP_Model: candidates head + per-route Customer MLP + 2-layer GRU + FC head
// R11: mlp_kernel FUSED into gru_res as Phase A. Each gru block (32 seqs)
// computes its own x2[24][32][32] into LDS: wave J handles t in {3J..3J+2}
// with a private [32][136] LDS scratch for the layer1->layer2 exchange (no
// intra-phase barriers), then one __syncthreads + sched_barrier(0) and the
// R10 recurrence (Phase B) reads x from LDS. Deletes the mlp dispatch, the
// 37MB x2 HBM write + readback, and mlp's duplicate weight-frag loads.
// LDS 118784 B: [0,69632)B = 8x per-wave scratch, reused in Phase B as
// h0l/h1l double buffers + bias table; [69632,118784)B = persistent x2l.
// Phase B unchanged from R10 (separate sigmoid/tanh chains, t=23 peel).
// ws layout: [0,344064) packed bf16 weights; hout fp32 at HOUT_BYTE.
// ---------------------------------------------------------------------------

#define NSEQ   24576   // 512 * 48
#define TSTEPS 24
#define SEQB   32      // sequences per gru block (2 tiles of 16)

typedef __attribute__((ext_vector_type(8))) short bf16x8;
typedef __attribute__((ext_vector_type(4))) float floatx4;

// packed-weight element offsets (uint16 units)
#define PK_W1    0
#define PK_W2    8192
#define PK_WIH0  12288
#define PK_WHH0  24576
#define PK_WIH1  73728
#define PK_WHH1  122880
#define PK_END   172032
#define HOUT_BYTE 38092800              // h1 final: [seq][128] fp32

// fused-kernel LDS layout (uint16 element offsets)
#define SCR_EL   4352                   // per-wave scratch: 32*136
#define H1L_EL   8704                   // h1 double buffer base (phase B)
#define BIAS_EL  17408                  // bias table base (float[1024])
#define X2L_EL   34816                  // x2l: [24][32][32] bf16
#define LDS_EL   59392                  // total elements (118784 B)

#define MFMA(a,b,c) c = __builtin_amdgcn_mfma_f32_16x16x32_bf16(a, b, c, 0, 0, 0)

__device__ __forceinline__ uint16_t f2bf(float f) {
  uint32_t u = __float_as_uint(f);
  u += 0x7FFFu + ((u >> 16) & 1u);           // RNE
  return (uint16_t)(u >> 16);
}
// packed f32x2 -> bf16x2 (RNE), single VALU op. lo half = first arg.
__device__ __forceinline__ uint32_t cvt_pk(float a, float b) {
  uint32_t r;
  asm("v_cvt_pk_bf16_f32 %0, %1, %2" : "=v"(r) : "v"(a), "v"(b));
  return r;
}
__device__ __forceinline__ float fast_sigmoid(float x) {
  float e = __builtin_amdgcn_exp2f(-1.4426950408889634f * x);
  return __builtin_amdgcn_rcpf(1.0f + e);
}
__device__ __forceinline__ float fast_tanh(float x) {
  float e = __builtin_amdgcn_exp2f(-2.8853900817779268f * x);
  return 2.0f * __builtin_amdgcn_rcpf(1.0f + e) - 1.0f;
}
__device__ __forceinline__ bf16x8 ldf(const uint16_t* p) {
  return *(const bf16x8*)p;
}

// ---------------------------------------------------------------------------
// Kernel 0: pack all weights to bf16 fragment layout. (unchanged)
// ---------------------------------------------------------------------------
__global__ __launch_bounds__(256) void pack_weights(
    const float* __restrict__ w1, const float* __restrict__ w2,
    const float* __restrict__ wih0, const float* __restrict__ whh0,
    const float* __restrict__ wih1, const float* __restrict__ whh1,
    uint16_t* __restrict__ ws) {
  int idx = blockIdx.x * 256 + threadIdx.x;
  if (idx >= PK_END) return;
  const float* W; int N, KB, Kreal, base;
  if      (idx <  8192) { W = w1;   N = 128; KB = 2; Kreal = 36;  base = 0; }
  else if (idx < 12288) { W = w2;   N = 32;  KB = 4; Kreal = 128; base = 8192; }
  else if (idx < 24576) { W = wih0; N = 384; KB = 1; Kreal = 32;  base = 12288; }
  else if (idx < 73728) { W = whh0; N = 384; KB = 4; Kreal = 128; base = 24576; }
  else if (idx < 122880){ W = wih1; N = 384; KB = 4; Kreal = 128; base = 73728; }
  else                  { W = whh1; N = 384; KB = 4; Kreal = 128; base = 122880; }
  int li = idx - base;
  int frag = li >> 9;
  int e = li & 511;
  int lane = e >> 3, j = e & 7;
  int kb = frag % KB, nt = frag / KB;
  int k = kb * 32 + (lane >> 4) * 8 + j;
  int n = nt * 16 + (lane & 15);
  float v = (k < Kreal) ? W[k * N + n] : 0.0f;
  ws[base + li] = f2bf(v);
}

// ---------------------------------------------------------------------------
// Kernel 1 (R11): FUSED customer-MLP + 2-layer GRU. Grid 768 x 512 threads.
// ---------------------------------------------------------------------------
__global__ __launch_bounds__(512, 2) void gru_fused(
    const float* __restrict__ customers, const float* __restrict__ b1,
    const float* __restrict__ b2, const uint16_t* __restrict__ wpk,
    const float* __restrict__ bih0, const float* __restrict__ bhh0,
    const float* __restrict__ bih1, const float* __restrict__ bhh1,
    float* __restrict__ hout) {
  __shared__ __align__(16) uint16_t lds[LDS_EL];
  const int seq0 = blockIdx.x * SEQB;
  const int tid = threadIdx.x;
  const int J = tid >> 6, l = tid & 63, q = l >> 4, c = l & 15;
  const int lo8 = l * 8;
  const int hbA = 4 * q;             // phase A: lane's 4 rows within a tile
  const int hb  = J * 16 + 4 * q;    // phase B: lane's 4 hidden cols

  // ================ Phase A: customer MLP, 32 seqs x 24 t ================
  {
    uint16_t* scr = lds + J * SCR_EL;       // private [32][136]
    uint16_t* x2l = lds + X2L_EL;           // [24][32][32]
    #pragma unroll 1
    for (int tt = 0; tt < 3; ++tt) {
      const int t = J * 3 + tt;             // this wave's timestep
      floatx4 acc[2][8];
      #pragma unroll
      for (int mi = 0; mi < 2; ++mi)
        #pragma unroll
        for (int nt = 0; nt < 8; ++nt) acc[mi][nt] = (floatx4){0.f, 0.f, 0.f, 0.f};

      #pragma unroll
      for (int mi = 0; mi < 2; ++mi) {
        const int seq = seq0 + mi * 16 + c;
        const float* xp = customers + (size_t)seq * 864 + t * 36;
        floatx4 u0 = *(const floatx4*)(xp + q * 8);
        floatx4 u1 = *(const floatx4*)(xp + q * 8 + 4);
        bf16x8 a0;
        { uint32_t* a0u = (uint32_t*)&a0;
          a0u[0] = cvt_pk(u0[0], u0[1]); a0u[1] = cvt_pk(u0[2], u0[3]);
          a0u[2] = cvt_pk(u1[0], u1[1]); a0u[3] = cvt_pk(u1[2], u1[3]); }
        bf16x8 a1x = (bf16x8){0,0,0,0,0,0,0,0};
        if (q == 0) {
          floatx4 u2 = *(const floatx4*)(xp + 32);
          uint32_t* a1u = (uint32_t*)&a1x;
          a1u[0] = cvt_pk(u2[0], u2[1]); a1u[1] = cvt_pk(u2[2], u2[3]);
        }
        #pragma unroll
        for (int nt = 0; nt < 8; ++nt) {
          bf16x8 bv0 = ldf(wpk + PK_W1 + (nt * 2 + 0) * 512 + lo8);
          bf16x8 bv1 = ldf(wpk + PK_W1 + (nt * 2 + 1) * 512 + lo8);
          MFMA(bv0, a0,  acc[mi][nt]);     // W1 as A, x as B -> D[hid][seq]
          MFMA(bv1, a1x, acc[mi][nt]);
        }
      }
      #pragma unroll
      for (int mi = 0; mi < 2; ++mi)
        #pragma unroll
        for (int nt = 0; nt < 8; ++nt) {
          const floatx4 bv = *(const floatx4*)(b1 + nt * 16 + hbA);
          float o0 = fast_tanh(acc[mi][nt][0] + bv[0]);
          float o1 = fast_tanh(acc[mi][nt][1] + bv[1]);
          float o2 = fast_tanh(acc[mi][nt][2] + bv[2]);
          float o3 = fast_tanh(acc[mi][nt][3] + bv[3]);
          uint2 pk; pk.x = cvt_pk(o0, o1); pk.y = cvt_pk(o2, o3);
          *(uint2*)&scr[(mi * 16 + c) * 136 + nt * 16 + hbA] = pk;
        }
      // same-wave scratch read-back (compiler inserts lgkmcnt)
      floatx4 acc2[2][2];
      #pragma unroll
      for (int mi = 0; mi < 2; ++mi)
        #pragma unroll
        for (int nt = 0; nt < 2; ++nt) acc2[mi][nt] = (floatx4){0.f, 0.f, 0.f, 0.f};
      #pragma unroll
      for (int kb = 0; kb < 4; ++kb) {
        bf16x8 av0 = ldf(&scr[(c)      * 136 + kb * 32 + q * 8]);
        bf16x8 av1 = ldf(&scr[(16 + c) * 136 + kb * 32 + q * 8]);
        #pragma unroll
        for (int nt = 0; nt < 2; ++nt) {
          bf16x8 bv = ldf(wpk + PK_W2 + (nt * 4 + kb) * 512 + lo8);
          MFMA(bv, av0, acc2[0][nt]);      // W2 as A, h as B -> D[out][seq]
          MFMA(bv, av1, acc2[1][nt]);
        }
      }
      #pragma unroll
      for (int mi = 0; mi < 2; ++mi)
        #pragma unroll
        for (int nt = 0; nt < 2; ++nt) {
          const floatx4 bv = *(const floatx4*)(b2 + nt * 16 + hbA);
          float o0 = fast_tanh(acc2[mi][nt][0] + bv[0]);
          float o1 = fast_tanh(acc2[mi][nt][1] + bv[1]);
          float o2 = fast_tanh(acc2[mi][nt][2] + bv[2]);
          float o3 = fast_tanh(acc2[mi][nt][3] + bv[3]);
          uint2 pk; pk.x = cvt_pk(o0, o1); pk.y = cvt_pk(o2, o3);
          *(uint2*)&x2l[t * 1024 + (mi * 16 + c) * 32 + nt * 16 + hbA] = pk;
        }
    }
  }
  __syncthreads();
  __builtin_amdgcn_sched_barrier(0);   // keep phase-B weight loads below

  // ================ Phase B: fused 2-layer GRU (R10 structure) ================
  const uint16_t* x2l = lds + X2L_EL;
  // zero h1[-1] (h1 buffer 0)
  for (int i = tid; i < 2176; i += 512) ((uint32_t*)(lds + H1L_EL))[i] = 0u;
  // bias table (float[8][128] at BIAS_EL)
  float* biasf = (float*)(lds + BIAS_EL);
  for (int i = tid; i < 1024; i += 512) {
    int g = i >> 7, k = i & 127;
    float v;
    if      (g == 0) v = bih0[k]       + bhh0[k];
    else if (g == 1) v = bih0[128 + k] + bhh0[128 + k];
    else if (g == 2) v = bih0[256 + k];
    else if (g == 3) v = bhh0[256 + k];
    else if (g == 4) v = bih1[k]       + bhh1[k];
    else if (g == 5) v = bih1[128 + k] + bhh1[128 + k];
    else if (g == 6) v = bih1[256 + k];
    else             v = bhh1[256 + k];
    biasf[g * 128 + k] = v;
  }

  // ---- this wave's weight fragments (A-operands) into VGPRs (39 frags) ----
  bf16x8 wi0[3], wh0[3][4], wi1[3][4], wh1[3][4];
  #pragma unroll
  for (int g = 0; g < 3; ++g) {
    wi0[g] = ldf(wpk + PK_WIH0 + (g * 8 + J) * 512 + lo8);
    #pragma unroll
    for (int kb = 0; kb < 4; ++kb) {
      wh0[g][kb] = ldf(wpk + PK_WHH0 + ((g * 8 + J) * 4 + kb) * 512 + lo8);
      wi1[g][kb] = ldf(wpk + PK_WIH1 + ((g * 8 + J) * 4 + kb) * 512 + lo8);
      wh1[g][kb] = ldf(wpk + PK_WHH1 + ((g * 8 + J) * 4 + kb) * 512 + lo8);
    }
  }

  floatx4 h0m0 = (floatx4){0.f,0.f,0.f,0.f}, h0m1 = (floatx4){0.f,0.f,0.f,0.f};
  floatx4 h1m0 = (floatx4){0.f,0.f,0.f,0.f}, h1m1 = (floatx4){0.f,0.f,0.f,0.f};

  __syncthreads();   // biasf + zeroed h1 buffer visible

  // ---- prologue: L0[0] with h0[-1]=0 (skip Whh MFMAs) -> h0 buffer 0 ----
  {
    bf16x8 ax_0 = ldf(x2l + (c)      * 32 + q * 8);          // x[0]
    bf16x8 ax_1 = ldf(x2l + (16 + c) * 32 + q * 8);
    #define GRU_PRO(TI, AX, H0M)                                            \
    {                                                                       \
      floatx4 aR = *(const floatx4*)&biasf[0 * 128 + hb];                   \
      floatx4 aZ = *(const floatx4*)&biasf[1 * 128 + hb];                   \
      floatx4 aN = *(const floatx4*)&biasf[2 * 128 + hb];                   \
      floatx4 aH = *(const floatx4*)&biasf[3 * 128 + hb];                   \
      MFMA(wi0[0], AX, aR); MFMA(wi0[1], AX, aZ); MFMA(wi0[2], AX, aN);     \
      float o[4];                                                           \
      _Pragma("unroll")                                                     \
      for (int e = 0; e < 4; ++e) {                                         \
        float r  = fast_sigmoid(aR[e]);                                     \
        float zz = fast_sigmoid(aZ[e]);                                     \
        float nn = fast_tanh(aN[e] + r * aH[e]);                            \
        o[e] = nn - zz * nn;                                                \
        H0M[e] = o[e];                                                      \
      }                                                                     \
      uint2 pk; pk.x = cvt_pk(o[0], o[1]); pk.y = cvt_pk(o[2], o[3]);       \
      *(uint2*)(lds + ((TI) * 16 + c) * 136 + hb) = pk;                     \
    }
    GRU_PRO(0, ax_0, h0m0)
    GRU_PRO(1, ax_1, h0m1)
    #undef GRU_PRO
  }
  __syncthreads();

  // per-tile phase body: {L1[t], L0[t+1]} for 16 seqs, accs reused across tiles
  #define GRU_TILE(TI, AX, H0M, H1M)                                        \
  {                                                                         \
    floatx4 aR1 = *(const floatx4*)&biasf[4 * 128 + hb];                    \
    floatx4 aZ1 = *(const floatx4*)&biasf[5 * 128 + hb];                    \
    floatx4 aN1 = *(const floatx4*)&biasf[6 * 128 + hb];                    \
    floatx4 aH1 = *(const floatx4*)&biasf[7 * 128 + hb];                    \
    floatx4 aR0 = *(const floatx4*)&biasf[0 * 128 + hb];                    \
    floatx4 aZ0 = *(const floatx4*)&biasf[1 * 128 + hb];                    \
    floatx4 aN0 = *(const floatx4*)&biasf[2 * 128 + hb];                    \
    floatx4 aH0 = *(const floatx4*)&biasf[3 * 128 + hb];                    \
    _Pragma("unroll")                                                       \
    for (int kb = 0; kb < 4; ++kb) {                                        \
      bf16x8 a0 = ldf(h0cur + ((TI) * 16 + c) * 136 + kb * 32 + q * 8);     \
      bf16x8 ah = ldf(h1prv + ((TI) * 16 + c) * 136 + kb * 32 + q * 8);     \
      MFMA(wi1[0][kb], a0, aR1); MFMA(wh1[0][kb], ah, aR1);                 \
      MFMA(wi1[1][kb], a0, aZ1); MFMA(wh1[1][kb], ah, aZ1);                 \
      MFMA(wi1[2][kb], a0, aN1); MFMA(wh1[2][kb], ah, aH1);                 \
      MFMA(wh0[0][kb], a0, aR0);                                            \
      MFMA(wh0[1][kb], a0, aZ0);                                            \
      MFMA(wh0[2][kb], a0, aH0);                                            \
    }                                                                       \
    MFMA(wi0[0], AX, aR0); MFMA(wi0[1], AX, aZ0); MFMA(wi0[2], AX, aN0);    \
    { /* L1 epilogue -> h1[t] */                                            \
      float o[4];                                                           \
      _Pragma("unroll")                                                     \
      for (int e = 0; e < 4; ++e) {                                         \
        float r  = fast_sigmoid(aR1[e]);                                    \
        float zz = fast_sigmoid(aZ1[e]);                                    \
        float nn = fast_tanh(aN1[e] + r * aH1[e]);                          \
        o[e] = nn + zz * (H1M[e] - nn);                                     \
        H1M[e] = o[e];                                                      \
      }                                                                     \
      uint2 pk; pk.x = cvt_pk(o[0], o[1]); pk.y = cvt_pk(o[2], o[3]);       \
      *(uint2*)(h1cur + ((TI) * 16 + c) * 136 + hb) = pk;                   \
    }                                                                       \
    { /* L0 epilogue -> h0[t+1] */                                          \
      float o[4];                                                           \
      _Pragma("unroll")                                                     \
      for (int e = 0; e < 4; ++e) {                                         \
        float r  = fast_sigmoid(aR0[e]);                                    \
        float zz = fast_sigmoid(aZ0[e]);                                    \
        float nn = fast_tanh(aN0[e] + r * aH0[e]);                          \
        o[e] = nn + zz * (H0M[e] - nn);                                     \
        H0M[e] = o[e];                                                      \
      }                                                                     \
      uint2 pk; pk.x = cvt_pk(o[0], o[1]); pk.y = cvt_pk(o[2], o[3]);       \
      *(uint2*)(h0nxt + ((TI) * 16 + c) * 136 + hb) = pk;                   \
    }                                                                       \
  }

  #pragma unroll 1
  for (int t = 0; t < TSTEPS - 1; ++t) {
    uint16_t* h0cur = lds + (t & 1) * SCR_EL;
    uint16_t* h1prv = lds + H1L_EL + (t & 1) * SCR_EL;
    uint16_t* h0nxt = lds + ((t + 1) & 1) * SCR_EL;
    uint16_t* h1cur = lds + H1L_EL + ((t + 1) & 1) * SCR_EL;
    bf16x8 ax_0 = ldf(x2l + (t + 1) * 1024 + (c)      * 32 + q * 8);
    bf16x8 ax_1 = ldf(x2l + (t + 1) * 1024 + (16 + c) * 32 + q * 8);

    GRU_TILE(0, ax_0, h0m0, h1m0)
    __builtin_amdgcn_sched_barrier(0);   // pin tile split: acc regs reused
    GRU_TILE(1, ax_1, h0m1, h1m1)

    __syncthreads();
  }
  #undef GRU_TILE

  // ---- peeled final phase t=23: L1 only, no LDS stores, no barrier ----
  {
    const uint16_t* h0cur = lds + ((TSTEPS - 1) & 1) * SCR_EL;
    const uint16_t* h1prv = lds + H1L_EL + ((TSTEPS - 1) & 1) * SCR_EL;
    #define GRU_LAST(TI, H1M)                                               \
    {                                                                       \
      floatx4 aR1 = *(const floatx4*)&biasf[4 * 128 + hb];                  \
      floatx4 aZ1 = *(const floatx4*)&biasf[5 * 128 + hb];                  \
      floatx4 aN1 = *(const floatx4*)&biasf[6 * 128 + hb];                  \
      floatx4 aH1 = *(const floatx4*)&biasf[7 * 128 + hb];                  \
      _Pragma("unroll")                                                     \
      for (int kb = 0; kb < 4; ++kb) {                                      \
        bf16x8 a0 = ldf(h0cur + ((TI) * 16 + c) * 136 + kb * 32 + q * 8);   \
        bf16x8 ah = ldf(h1prv + ((TI) * 16 + c) * 136 + kb * 32 + q * 8);   \
        MFMA(wi1[0][kb], a0, aR1); MFMA(wh1[0][kb], ah, aR1);               \
        MFMA(wi1[1][kb], a0, aZ1); MFMA(wh1[1][kb], ah, aZ1);               \
        MFMA(wi1[2][kb], a0, aN1); MFMA(wh1[2][kb], ah, aH1);               \
      }                                                                     \
      _Pragma("unroll")                                                     \
      for (int e = 0; e < 4; ++e) {                                         \
        float r  = fast_sigmoid(aR1[e]);                                    \
        float zz = fast_sigmoid(aZ1[e]);                                    \
        float nn = fast_tanh(aN1[e] + r * aH1[e]);                          \
        H1M[e] = nn + zz * (H1M[e] - nn);                                   \
      }                                                                     \
    }
    GRU_LAST(0, h1m0)
    GRU_LAST(1, h1m1)
    #undef GRU_LAST
  }

  *(floatx4*)(hout + (size_t)(seq0 + c) * 128 + hb) = h1m0;
  *(floatx4*)(hout + (size_t)(seq0 + 16 + c) * 128 + hb) = h1m1;
}

// ---------------------------------------------------------------------------
// Kernel 2: mean over routes + candidate head + fc1/fc2/fc3 (unchanged)
// ---------------------------------------------------------------------------
__global__ __launch_bounds__(192) void final_kernel(
    const float* __restrict__ hout, const float* __restrict__ cands,
    const float* __restrict__ cw, const float* __restrict__ cb,
    const float* __restrict__ f1w, const float* __restrict__ f1b,
    const float* __restrict__ f2w, const float* __restrict__ f2b,
    const float* __restrict__ f3w, const float* __restrict__ f3b,
    float* __restrict__ out) {
  __shared__ float hc[192];
  __shared__ float v1[128];
  __shared__ float v2[128];
  __shared__ float red[128];
  const int b = blockIdx.x, tid = threadIdx.x;
  if (tid < 128) {
    float s = 0.f;
    const float* hp = hout + (size_t)(b * 48) * 128 + tid;
    #pragma unroll 4
    for (int r = 0; r < 48; ++r) s += hp[r * 128];
    hc[tid] = s * (1.0f / 48.0f);
  } else {
    int j = tid - 128;
    float s = cb[j];
    const float* cp = cands + b * 72;
    #pragma unroll 8
    for (int k = 0; k < 72; ++k) s += cp[k] * cw[k * 64 + j];
    hc[128 + j] = s;
  }
  __syncthreads();
  if (tid < 128) {
    float s = f1b[tid];
    for (int k = 0; k < 192; ++k) s += hc[k] * f1w[k * 128 + tid];
    v1[tid] = fast_tanh(s);
  }
  __syncthreads();
  if (tid < 128) {
    float s = f2b[tid];
    for (int k = 0; k < 128; ++k) s += v1[k] * f2w[k * 128 + tid];
    v2[tid] = fast_tanh(s);
  }
  __syncthreads();
  if (tid < 128) red[tid] = v2[tid] * f3w[tid];
  __syncthreads();
  if (tid < 64) {
    float s = red[tid] + red[tid + 64];
    s += __shfl_down(s, 32);
    s += __shfl_down(s, 16);
    s += __shfl_down(s, 8);
    s += __shfl_down(s, 4);
    s += __shfl_down(s, 2);
    s += __shfl_down(s, 1);
    if (tid == 0) out[b] = s + f3b[0];
  }
}

// ---------------------------------------------------------------------------
extern "C" void kernel_launch(void* const* d_in, const int* in_sizes, int n_in,
                              void* d_out, int out_size, void* d_ws, size_t ws_size,
                              hipStream_t stream) {
  const float* cand  = (const float*)d_in[0];
  const float* cust  = (const float*)d_in[1];
  const float* w1    = (const float*)d_in[2];
  const float* b1    = (const float*)d_in[3];
  const float* w2    = (const float*)d_in[4];
  const float* b2    = (const float*)d_in[5];
  const float* wih0  = (const float*)d_in[6];
  const float* whh0  = (const float*)d_in[7];
  const float* bih0  = (const float*)d_in[8];
  const float* bhh0  = (const float*)d_in[9];
  const float* wih1  = (const float*)d_in[10];
  const float* whh1  = (const float*)d_in[11];
  const float* bih1  = (const float*)d_in[12];
  const float* bhh1  = (const float*)d_in[13];
  const float* cw    = (const float*)d_in[14];
  const float* cb    = (const float*)d_in[15];
  const float* f1w   = (const float*)d_in[16];
  const float* f1b   = (const float*)d_in[17];
  const float* f2w   = (const float*)d_in[18];
  const float* f2b   = (const float*)d_in[19];
  const float* f3w   = (const float*)d_in[20];
  const float* f3b   = (const float*)d_in[21];

  uint16_t* wsp = (uint16_t*)d_ws;
  float* hout = (float*)((char*)d_ws + HOUT_BYTE);
  float* outp = (float*)d_out;

  pack_weights<<<(PK_END + 255) / 256, 256, 0, stream>>>(w1, w2, wih0, whh0, wih1, whh1, wsp);
  gru_fused<<<NSEQ / SEQB, 512, 0, stream>>>(cust, b1, b2, wsp, bih0, bhh0, bih1, bhh1, hout);
  final_kernel<<<512, 192, 0, stream>>>(hout, cand, cw, cb, f1w, f1b, f2w, f2b, f3w, f3b, outp);
}

// Round 10
// 387.906 us; speedup vs baseline: 1.0823x; 1.0425x over previous
//
#include <hip/hip_runtime.h>
#include <stdint.h>

// ---------------------------------------------------------------------------
// MLP_Model: candidates head + per-route Customer MLP + 2-layer GRU + FC head
// R13 = R12 with the LDS aliasing bug fixed: R12 staged the Phase A bias
// table at BIAS_EL=17408, which is INSIDE wave 4's Phase A scratch region
// [0,34816) -> clobbered biases, absmax 0.207. Phase A biases now live in a
// dedicated region BIASA_EL=59392 past all Phase A/B buffers (LDS 119424 B,
// still 1 block/CU). R12 content otherwise unchanged: W1/W2 frags hoisted to
// VGPRs before the tt loop, customer loads issued at iteration top, t=8*tt+J.
// Phase B (GRU recurrence) unchanged from R10/R11.
// ws layout: [0,344064) packed bf16 weights; hout fp32 at HOUT_BYTE.
// ---------------------------------------------------------------------------

#define NSEQ   24576   // 512 * 48
#define TSTEPS 24
#define SEQB   32      // sequences per gru block (2 tiles of 16)

typedef __attribute__((ext_vector_type(8))) short bf16x8;
typedef __attribute__((ext_vector_type(4))) float floatx4;

// packed-weight element offsets (uint16 units)
#define PK_W1    0
#define PK_W2    8192
#define PK_WIH0  12288
#define PK_WHH0  24576
#define PK_WIH1  73728
#define PK_WHH1  122880
#define PK_END   172032
#define HOUT_BYTE 38092800              // h1 final: [seq][128] fp32

// fused-kernel LDS layout (uint16 element offsets)
#define SCR_EL   4352                   // per-wave scratch: 32*136 (J=0..7 -> [0,34816))
#define H1L_EL   8704                   // h1 double buffer base (phase B; aliases scr[2..3])
#define BIAS_EL  17408                  // phase B bias table (written AFTER phase A)
#define X2L_EL   34816                  // x2l: [24][32][32] bf16
#define BIASA_EL 59392                  // phase A bias table: float[160] (320 el)
#define LDS_EL   59712                  // total elements (119424 B)

#define MFMA(a,b,c) c = __builtin_amdgcn_mfma_f32_16x16x32_bf16(a, b, c, 0, 0, 0)

__device__ __forceinline__ uint16_t f2bf(float f) {
  uint32_t u = __float_as_uint(f);
  u += 0x7FFFu + ((u >> 16) & 1u);           // RNE
  return (uint16_t)(u >> 16);
}
// packed f32x2 -> bf16x2 (RNE), single VALU op. lo half = first arg.
__device__ __forceinline__ uint32_t cvt_pk(float a, float b) {
  uint32_t r;
  asm("v_cvt_pk_bf16_f32 %0, %1, %2" : "=v"(r) : "v"(a), "v"(b));
  return r;
}
__device__ __forceinline__ float fast_sigmoid(float x) {
  float e = __builtin_amdgcn_exp2f(-1.4426950408889634f * x);
  return __builtin_amdgcn_rcpf(1.0f + e);
}
__device__ __forceinline__ float fast_tanh(float x) {
  float e = __builtin_amdgcn_exp2f(-2.8853900817779268f * x);
  return 2.0f * __builtin_amdgcn_rcpf(1.0f + e) - 1.0f;
}
__device__ __forceinline__ bf16x8 ldf(const uint16_t* p) {
  return *(const bf16x8*)p;
}

// ---------------------------------------------------------------------------
// Kernel 0: pack all weights to bf16 fragment layout. (unchanged)
// ---------------------------------------------------------------------------
__global__ __launch_bounds__(256) void pack_weights(
    const float* __restrict__ w1, const float* __restrict__ w2,
    const float* __restrict__ wih0, const float* __restrict__ whh0,
    const float* __restrict__ wih1, const float* __restrict__ whh1,
    uint16_t* __restrict__ ws) {
  int idx = blockIdx.x * 256 + threadIdx.x;
  if (idx >= PK_END) return;
  const float* W; int N, KB, Kreal, base;
  if      (idx <  8192) { W = w1;   N = 128; KB = 2; Kreal = 36;  base = 0; }
  else if (idx < 12288) { W = w2;   N = 32;  KB = 4; Kreal = 128; base = 8192; }
  else if (idx < 24576) { W = wih0; N = 384; KB = 1; Kreal = 32;  base = 12288; }
  else if (idx < 73728) { W = whh0; N = 384; KB = 4; Kreal = 128; base = 24576; }
  else if (idx < 122880){ W = wih1; N = 384; KB = 4; Kreal = 128; base = 73728; }
  else                  { W = whh1; N = 384; KB = 4; Kreal = 128; base = 122880; }
  int li = idx - base;
  int frag = li >> 9;
  int e = li & 511;
  int lane = e >> 3, j = e & 7;
  int kb = frag % KB, nt = frag / KB;
  int k = kb * 32 + (lane >> 4) * 8 + j;
  int n = nt * 16 + (lane & 15);
  float v = (k < Kreal) ? W[k * N + n] : 0.0f;
  ws[base + li] = f2bf(v);
}

// ---------------------------------------------------------------------------
// Kernel 1 (R13): FUSED customer-MLP + 2-layer GRU. Grid 768 x 512 threads.
// ---------------------------------------------------------------------------
__global__ __launch_bounds__(512, 2) void gru_fused(
    const float* __restrict__ customers, const float* __restrict__ b1,
    const float* __restrict__ b2, const uint16_t* __restrict__ wpk,
    const float* __restrict__ bih0, const float* __restrict__ bhh0,
    const float* __restrict__ bih1, const float* __restrict__ bhh1,
    float* __restrict__ hout) {
  __shared__ __align__(16) uint16_t lds[LDS_EL];
  const int seq0 = blockIdx.x * SEQB;
  const int tid = threadIdx.x;
  const int J = tid >> 6, l = tid & 63, q = l >> 4, c = l & 15;
  const int lo8 = l * 8;
  const int hbA = 4 * q;             // phase A: lane's 4 rows within a tile
  const int hb  = J * 16 + 4 * q;    // phase B: lane's 4 hidden cols

  // ---- stage b1/b2 into dedicated LDS region (no aliasing with scratch) ----
  float* biasA = (float*)(lds + BIASA_EL);
  if (tid < 160) biasA[tid] = (tid < 128) ? b1[tid] : b2[tid - 128];
  __syncthreads();

  // ================ Phase A: customer MLP, 32 seqs x 24 t ================
  {
    uint16_t* scr = lds + J * SCR_EL;       // private [32][136]
    uint16_t* x2l = lds + X2L_EL;           // [24][32][32]

    // hoisted weight fragments: W1 (16) + W2 (8) = 96 VGPR, dead after A
    bf16x8 w1f[16], w2f[8];
    #pragma unroll
    for (int i = 0; i < 16; ++i) w1f[i] = ldf(wpk + PK_W1 + i * 512 + lo8);
    #pragma unroll
    for (int i = 0; i < 8; ++i)  w2f[i] = ldf(wpk + PK_W2 + i * 512 + lo8);

    #pragma unroll 1
    for (int tt = 0; tt < 3; ++tt) {
      const int t = tt * 8 + J;             // this wave's timestep
      // all customer loads for this iteration, issued up front
      floatx4 u0[2], u1[2], u2[2];
      #pragma unroll
      for (int mi = 0; mi < 2; ++mi) {
        const float* xp = customers + (size_t)(seq0 + mi * 16 + c) * 864 + t * 36;
        u0[mi] = *(const floatx4*)(xp + q * 8);
        u1[mi] = *(const floatx4*)(xp + q * 8 + 4);
        u2[mi] = *(const floatx4*)(xp + 32);   // in-bounds; used when q==0
      }

      floatx4 acc[2][8];
      #pragma unroll
      for (int mi = 0; mi < 2; ++mi)
        #pragma unroll
        for (int nt = 0; nt < 8; ++nt) acc[mi][nt] = (floatx4){0.f, 0.f, 0.f, 0.f};

      #pragma unroll
      for (int mi = 0; mi < 2; ++mi) {
        bf16x8 a0;
        { uint32_t* a0u = (uint32_t*)&a0;
          a0u[0] = cvt_pk(u0[mi][0], u0[mi][1]); a0u[1] = cvt_pk(u0[mi][2], u0[mi][3]);
          a0u[2] = cvt_pk(u1[mi][0], u1[mi][1]); a0u[3] = cvt_pk(u1[mi][2], u1[mi][3]); }
        bf16x8 a1x = (bf16x8){0,0,0,0,0,0,0,0};
        if (q == 0) {
          uint32_t* a1u = (uint32_t*)&a1x;
          a1u[0] = cvt_pk(u2[mi][0], u2[mi][1]); a1u[1] = cvt_pk(u2[mi][2], u2[mi][3]);
        }
        #pragma unroll
        for (int nt = 0; nt < 8; ++nt) {
          MFMA(w1f[nt * 2 + 0], a0,  acc[mi][nt]);   // W1 as A -> D[hid][seq]
          MFMA(w1f[nt * 2 + 1], a1x, acc[mi][nt]);
        }
      }
      #pragma unroll
      for (int mi = 0; mi < 2; ++mi)
        #pragma unroll
        for (int nt = 0; nt < 8; ++nt) {
          const floatx4 bv = *(const floatx4*)&biasA[nt * 16 + hbA];
          float o0 = fast_tanh(acc[mi][nt][0] + bv[0]);
          float o1 = fast_tanh(acc[mi][nt][1] + bv[1]);
          float o2 = fast_tanh(acc[mi][nt][2] + bv[2]);
          float o3 = fast_tanh(acc[mi][nt][3] + bv[3]);
          uint2 pk; pk.x = cvt_pk(o0, o1); pk.y = cvt_pk(o2, o3);
          *(uint2*)&scr[(mi * 16 + c) * 136 + nt * 16 + hbA] = pk;
        }
      // same-wave scratch read-back (compiler inserts lgkmcnt)
      floatx4 acc2[2][2];
      #pragma unroll
      for (int mi = 0; mi < 2; ++mi)
        #pragma unroll
        for (int nt = 0; nt < 2; ++nt) acc2[mi][nt] = (floatx4){0.f, 0.f, 0.f, 0.f};
      #pragma unroll
      for (int kb = 0; kb < 4; ++kb) {
        bf16x8 av0 = ldf(&scr[(c)      * 136 + kb * 32 + q * 8]);
        bf16x8 av1 = ldf(&scr[(16 + c) * 136 + kb * 32 + q * 8]);
        #pragma unroll
        for (int nt = 0; nt < 2; ++nt) {
          MFMA(w2f[nt * 4 + kb], av0, acc2[0][nt]);  // W2 as A -> D[out][seq]
          MFMA(w2f[nt * 4 + kb], av1, acc2[1][nt]);
        }
      }
      #pragma unroll
      for (int mi = 0; mi < 2; ++mi)
        #pragma unroll
        for (int nt = 0; nt < 2; ++nt) {
          const floatx4 bv = *(const floatx4*)&biasA[128 + nt * 16 + hbA];
          float o0 = fast_tanh(acc2[mi][nt][0] + bv[0]);
          float o1 = fast_tanh(acc2[mi][nt][1] + bv[1]);
          float o2 = fast_tanh(acc2[mi][nt][2] + bv[2]);
          float o3 = fast_tanh(acc2[mi][nt][3] + bv[3]);
          uint2 pk; pk.x = cvt_pk(o0, o1); pk.y = cvt_pk(o2, o3);
          *(uint2*)&x2l[t * 1024 + (mi * 16 + c) * 32 + nt * 16 + hbA] = pk;
        }
    }
  }
  __syncthreads();
  __builtin_amdgcn_sched_barrier(0);   // keep phase-B weight loads below

  // ================ Phase B: fused 2-layer GRU (R10 structure) ================
  const uint16_t* x2l = lds + X2L_EL;
  // zero h1[-1] (h1 buffer 0)
  for (int i = tid; i < 2176; i += 512) ((uint32_t*)(lds + H1L_EL))[i] = 0u;
  // bias table (float[8][128] at BIAS_EL; safe now — Phase A is done)
  float* biasf = (float*)(lds + BIAS_EL);
  for (int i = tid; i < 1024; i += 512) {
    int g = i >> 7, k = i & 127;
    float v;
    if      (g == 0) v = bih0[k]       + bhh0[k];
    else if (g == 1) v = bih0[128 + k] + bhh0[128 + k];
    else if (g == 2) v = bih0[256 + k];
    else if (g == 3) v = bhh0[256 + k];
    else if (g == 4) v = bih1[k]       + bhh1[k];
    else if (g == 5) v = bih1[128 + k] + bhh1[128 + k];
    else if (g == 6) v = bih1[256 + k];
    else             v = bhh1[256 + k];
    biasf[g * 128 + k] = v;
  }

  // ---- this wave's weight fragments (A-operands) into VGPRs (39 frags) ----
  bf16x8 wi0[3], wh0[3][4], wi1[3][4], wh1[3][4];
  #pragma unroll
  for (int g = 0; g < 3; ++g) {
    wi0[g] = ldf(wpk + PK_WIH0 + (g * 8 + J) * 512 + lo8);
    #pragma unroll
    for (int kb = 0; kb < 4; ++kb) {
      wh0[g][kb] = ldf(wpk + PK_WHH0 + ((g * 8 + J) * 4 + kb) * 512 + lo8);
      wi1[g][kb] = ldf(wpk + PK_WIH1 + ((g * 8 + J) * 4 + kb) * 512 + lo8);
      wh1[g][kb] = ldf(wpk + PK_WHH1 + ((g * 8 + J) * 4 + kb) * 512 + lo8);
    }
  }

  floatx4 h0m0 = (floatx4){0.f,0.f,0.f,0.f}, h0m1 = (floatx4){0.f,0.f,0.f,0.f};
  floatx4 h1m0 = (floatx4){0.f,0.f,0.f,0.f}, h1m1 = (floatx4){0.f,0.f,0.f,0.f};

  __syncthreads();   // biasf + zeroed h1 buffer visible

  // ---- prologue: L0[0] with h0[-1]=0 (skip Whh MFMAs) -> h0 buffer 0 ----
  {
    bf16x8 ax_0 = ldf(x2l + (c)      * 32 + q * 8);          // x[0]
    bf16x8 ax_1 = ldf(x2l + (16 + c) * 32 + q * 8);
    #define GRU_PRO(TI, AX, H0M)                                            \
    {                                                                       \
      floatx4 aR = *(const floatx4*)&biasf[0 * 128 + hb];                   \
      floatx4 aZ = *(const floatx4*)&biasf[1 * 128 + hb];                   \
      floatx4 aN = *(const floatx4*)&biasf[2 * 128 + hb];                   \
      floatx4 aH = *(const floatx4*)&biasf[3 * 128 + hb];                   \
      MFMA(wi0[0], AX, aR); MFMA(wi0[1], AX, aZ); MFMA(wi0[2], AX, aN);     \
      float o[4];                                                           \
      _Pragma("unroll")                                                     \
      for (int e = 0; e < 4; ++e) {                                         \
        float r  = fast_sigmoid(aR[e]);                                     \
        float zz = fast_sigmoid(aZ[e]);                                     \
        float nn = fast_tanh(aN[e] + r * aH[e]);                            \
        o[e] = nn - zz * nn;                                                \
        H0M[e] = o[e];                                                      \
      }                                                                     \
      uint2 pk; pk.x = cvt_pk(o[0], o[1]); pk.y = cvt_pk(o[2], o[3]);       \
      *(uint2*)(lds + ((TI) * 16 + c) * 136 + hb) = pk;                     \
    }
    GRU_PRO(0, ax_0, h0m0)
    GRU_PRO(1, ax_1, h0m1)
    #undef GRU_PRO
  }
  __syncthreads();

  // per-tile phase body: {L1[t], L0[t+1]} for 16 seqs, accs reused across tiles
  #define GRU_TILE(TI, AX, H0M, H1M)                                        \
  {                                                                         \
    floatx4 aR1 = *(const floatx4*)&biasf[4 * 128 + hb];                    \
    floatx4 aZ1 = *(const floatx4*)&biasf[5 * 128 + hb];                    \
    floatx4 aN1 = *(const floatx4*)&biasf[6 * 128 + hb];                    \
    floatx4 aH1 = *(const floatx4*)&biasf[7 * 128 + hb];                    \
    floatx4 aR0 = *(const floatx4*)&biasf[0 * 128 + hb];                    \
    floatx4 aZ0 = *(const floatx4*)&biasf[1 * 128 + hb];                    \
    floatx4 aN0 = *(const floatx4*)&biasf[2 * 128 + hb];                    \
    floatx4 aH0 = *(const floatx4*)&biasf[3 * 128 + hb];                    \
    _Pragma("unroll")                                                       \
    for (int kb = 0; kb < 4; ++kb) {                                        \
      bf16x8 a0 = ldf(h0cur + ((TI) * 16 + c) * 136 + kb * 32 + q * 8);     \
      bf16x8 ah = ldf(h1prv + ((TI) * 16 + c) * 136 + kb * 32 + q * 8);     \
      MFMA(wi1[0][kb], a0, aR1); MFMA(wh1[0][kb], ah, aR1);                 \
      MFMA(wi1[1][kb], a0, aZ1); MFMA(wh1[1][kb], ah, aZ1);                 \
      MFMA(wi1[2][kb], a0, aN1); MFMA(wh1[2][kb], ah, aH1);                 \
      MFMA(wh0[0][kb], a0, aR0);                                            \
      MFMA(wh0[1][kb], a0, aZ0);                                            \
      MFMA(wh0[2][kb], a0, aH0);                                            \
    }                                                                       \
    MFMA(wi0[0], AX, aR0); MFMA(wi0[1], AX, aZ0); MFMA(wi0[2], AX, aN0);    \
    { /* L1 epilogue -> h1[t] */                                            \
      float o[4];                                                           \
      _Pragma("unroll")                                                     \
      for (int e = 0; e < 4; ++e) {                                         \
        float r  = fast_sigmoid(aR1[e]);                                    \
        float zz = fast_sigmoid(aZ1[e]);                                    \
        float nn = fast_tanh(aN1[e] + r * aH1[e]);                          \
        o[e] = nn + zz * (H1M[e] - nn);                                     \
        H1M[e] = o[e];                                                      \
      }                                                                     \
      uint2 pk; pk.x = cvt_pk(o[0], o[1]); pk.y = cvt_pk(o[2], o[3]);       \
      *(uint2*)(h1cur + ((TI) * 16 + c) * 136 + hb) = pk;                   \
    }                                                                       \
    { /* L0 epilogue -> h0[t+1] */                                          \
      float o[4];                                                           \
      _Pragma("unroll")                                                     \
      for (int e = 0; e < 4; ++e) {                                         \
        float r  = fast_sigmoid(aR0[e]);                                    \
        float zz = fast_sigmoid(aZ0[e]);                                    \
        float nn = fast_tanh(aN0[e] + r * aH0[e]);                          \
        o[e] = nn + zz * (H0M[e] - nn);                                     \
        H0M[e] = o[e];                                                      \
      }                                                                     \
      uint2 pk; pk.x = cvt_pk(o[0], o[1]); pk.y = cvt_pk(o[2], o[3]);       \
      *(uint2*)(h0nxt + ((TI) * 16 + c) * 136 + hb) = pk;                   \
    }                                                                       \
  }

  #pragma unroll 1
  for (int t = 0; t < TSTEPS - 1; ++t) {
    uint16_t* h0cur = lds + (t & 1) * SCR_EL;
    uint16_t* h1prv = lds + H1L_EL + (t & 1) * SCR_EL;
    uint16_t* h0nxt = lds + ((t + 1) & 1) * SCR_EL;
    uint16_t* h1cur = lds + H1L_EL + ((t + 1) & 1) * SCR_EL;
    bf16x8 ax_0 = ldf(x2l + (t + 1) * 1024 + (c)      * 32 + q * 8);
    bf16x8 ax_1 = ldf(x2l + (t + 1) * 1024 + (16 + c) * 32 + q * 8);

    GRU_TILE(0, ax_0, h0m0, h1m0)
    __builtin_amdgcn_sched_barrier(0);   // pin tile split: acc regs reused
    GRU_TILE(1, ax_1, h0m1, h1m1)

    __syncthreads();
  }
  #undef GRU_TILE

  // ---- peeled final phase t=23: L1 only, no LDS stores, no barrier ----
  {
    const uint16_t* h0cur = lds + ((TSTEPS - 1) & 1) * SCR_EL;
    const uint16_t* h1prv = lds + H1L_EL + ((TSTEPS - 1) & 1) * SCR_EL;
    #define GRU_LAST(TI, H1M)                                               \
    {                                                                       \
      floatx4 aR1 = *(const floatx4*)&biasf[4 * 128 + hb];                  \
      floatx4 aZ1 = *(const floatx4*)&biasf[5 * 128 + hb];                  \
      floatx4 aN1 = *(const floatx4*)&biasf[6 * 128 + hb];                  \
      floatx4 aH1 = *(const floatx4*)&biasf[7 * 128 + hb];                  \
      _Pragma("unroll")                                                     \
      for (int kb = 0; kb < 4; ++kb) {                                      \
        bf16x8 a0 = ldf(h0cur + ((TI) * 16 + c) * 136 + kb * 32 + q * 8);   \
        bf16x8 ah = ldf(h1prv + ((TI) * 16 + c) * 136 + kb * 32 + q * 8);   \
        MFMA(wi1[0][kb], a0, aR1); MFMA(wh1[0][kb], ah, aR1);               \
        MFMA(wi1[1][kb], a0, aZ1); MFMA(wh1[1][kb], ah, aZ1);               \
        MFMA(wi1[2][kb], a0, aN1); MFMA(wh1[2][kb], ah, aH1);               \
      }                                                                     \
      _Pragma("unroll")                                                     \
      for (int e = 0; e < 4; ++e) {                                         \
        float r  = fast_sigmoid(aR1[e]);                                    \
        float zz = fast_sigmoid(aZ1[e]);                                    \
        float nn = fast_tanh(aN1[e] + r * aH1[e]);                          \
        H1M[e] = nn + zz * (H1M[e] - nn);                                   \
      }                                                                     \
    }
    GRU_LAST(0, h1m0)
    GRU_LAST(1, h1m1)
    #undef GRU_LAST
  }

  *(floatx4*)(hout + (size_t)(seq0 + c) * 128 + hb) = h1m0;
  *(floatx4*)(hout + (size_t)(seq0 + 16 + c) * 128 + hb) = h1m1;
}

// ---------------------------------------------------------------------------
// Kernel 2: mean over routes + candidate head + fc1/fc2/fc3 (unchanged)
// ---------------------------------------------------------------------------
__global__ __launch_bounds__(192) void final_kernel(
    const float* __restrict__ hout, const float* __restrict__ cands,
    const float* __restrict__ cw, const float* __restrict__ cb,
    const float* __restrict__ f1w, const float* __restrict__ f1b,
    const float* __restrict__ f2w, const float* __restrict__ f2b,
    const float* __restrict__ f3w, const float* __restrict__ f3b,
    float* __restrict__ out) {
  __shared__ float hc[192];
  __shared__ float v1[128];
  __shared__ float v2[128];
  __shared__ float red[128];
  const int b = blockIdx.x, tid = threadIdx.x;
  if (tid < 128) {
    float s = 0.f;
    const float* hp = hout + (size_t)(b * 48) * 128 + tid;
    #pragma unroll 4
    for (int r = 0; r < 48; ++r) s += hp[r * 128];
    hc[tid] = s * (1.0f / 48.0f);
  } else {
    int j = tid - 128;
    float s = cb[j];
    const float* cp = cands + b * 72;
    #pragma unroll 8
    for (int k = 0; k < 72; ++k) s += cp[k] * cw[k * 64 + j];
    hc[128 + j] = s;
  }
  __syncthreads();
  if (tid < 128) {
    float s = f1b[tid];
    for (int k = 0; k < 192; ++k) s += hc[k] * f1w[k * 128 + tid];
    v1[tid] = fast_tanh(s);
  }
  __syncthreads();
  if (tid < 128) {
    float s = f2b[tid];
    for (int k = 0; k < 128; ++k) s += v1[k] * f2w[k * 128 + tid];
    v2[tid] = fast_tanh(s);
  }
  __syncthreads();
  if (tid < 128) red[tid] = v2[tid] * f3w[tid];
  __syncthreads();
  if (tid < 64) {
    float s = red[tid] + red[tid + 64];
    s += __shfl_down(s, 32);
    s += __shfl_down(s, 16);
    s += __shfl_down(s, 8);
    s += __shfl_down(s, 4);
    s += __shfl_down(s, 2);
    s += __shfl_down(s, 1);
    if (tid == 0) out[b] = s + f3b[0];
  }
}

// ---------------------------------------------------------------------------
extern "C" void kernel_launch(void* const* d_in, const int* in_sizes, int n_in,
                              void* d_out, int out_size, void* d_ws, size_t ws_size,
                              hipStream_t stream) {
  const float* cand  = (const float*)d_in[0];
  const float* cust  = (const float*)d_in[1];
  const float* w1    = (const float*)d_in[2];
  const float* b1    = (const float*)d_in[3];
  const float* w2    = (const float*)d_in[4];
  const float* b2    = (const float*)d_in[5];
  const float* wih0  = (const float*)d_in[6];
  const float* whh0  = (const float*)d_in[7];
  const float* bih0  = (const float*)d_in[8];
  const float* bhh0  = (const float*)d_in[9];
  const float* wih1  = (const float*)d_in[10];
  const float* whh1  = (const float*)d_in[11];
  const float* bih1  = (const float*)d_in[12];
  const float* bhh1  = (const float*)d_in[13];
  const float* cw    = (const float*)d_in[14];
  const float* cb    = (const float*)d_in[15];
  const float* f1w   = (const float*)d_in[16];
  const float* f1b   = (const float*)d_in[17];
  const float* f2w   = (const float*)d_in[18];
  const float* f2b   = (const float*)d_in[19];
  const float* f3w   = (const float*)d_in[20];
  const float* f3b   = (const float*)d_in[21];

  uint16_t* wsp = (uint16_t*)d_ws;
  float* hout = (float*)((char*)d_ws + HOUT_BYTE);
  float* outp = (float*)d_out;

  pack_weights<<<(PK_END + 255) / 256, 256, 0, stream>>>(w1, w2, wih0, whh0, wih1, whh1, wsp);
  gru_fused<<<NSEQ / SEQB, 512, 0, stream>>>(cust, b1, b2, wsp, bih0, bhh0, bih1, bhh1, hout);
  final_kernel<<<512, 192, 0, stream>>>(hout, cand, cw, cb, f1w, f1b, f2w, f2b, f3w, f3b, outp);
}